// Round 3
// baseline (908.861 us; speedup 1.0000x reference)
//
#include <hip/hip_runtime.h>
#include <hip/hip_bf16.h>

// Problem constants (from reference)
#define NNODES 10000
#define NEDGES 320000
#define INF_   1280
#define HID_   128
#define HEADS_ 4
#define OUTF_  500
#define HC_    512          // HEADS_*HID_
#define NEG_SLOPE 0.2f
#define BN_EPS 1e-5f

typedef __attribute__((ext_vector_type(8))) short short8x;
typedef __attribute__((ext_vector_type(4))) float f32x4;
typedef unsigned short ushort_t;
typedef unsigned int uint_t;

__device__ __forceinline__ ushort_t f2bf(float f) {
    uint_t u = __float_as_uint(f);
    u = (u + 0x7fffu + ((u >> 16) & 1u)) >> 16;   // round-to-nearest-even
    return (ushort_t)u;
}
__device__ __forceinline__ float bf_lo(uint_t p) { return __uint_as_float(p << 16); }
__device__ __forceinline__ float bf_hi(uint_t p) { return __uint_as_float(p & 0xffff0000u); }
__device__ __forceinline__ float lrelu(float x) { return (x >= 0.f) ? x : NEG_SLOPE * x; }
__device__ __forceinline__ uint_t pack_bf16_rn(float a, float b) {
    __hip_bfloat162 h = __float22bfloat162_rn(make_float2(a, b));  // hw packed cvt, RNE
    return *(uint_t*)&h;
}

// ---------------------------------------------------------------------------
// convall: x->bf16 + 3 weight transposes + zero counts + zero BN partials.
// (dispatch-count reduction: absorbs the old zero_kernel)
// ---------------------------------------------------------------------------
#define CVX (NNODES * INF_ / 4)        // 3,200,000 float4 chunks of x
#define CN1 (HC_ * INF_)
#define CN2 (HC_ * HC_)
#define CN3 (HC_ * HC_)                // Wt3 (padded rows)
#define CZC (NNODES / 4)               // counts as uint4 (10000 ints = 2500)
#define CZP (4 * 64 * HC_ / 4)         // 4 psum buffers as uint4 (32768)
__global__ void convall_kernel(const float* __restrict__ x,
                               const float* __restrict__ W1,
                               const float* __restrict__ W2,
                               const float* __restrict__ W3,
                               ushort_t* __restrict__ x_bf,
                               ushort_t* __restrict__ Wt1,
                               ushort_t* __restrict__ Wt2,
                               ushort_t* __restrict__ Wt3,
                               uint4* __restrict__ zc,     // counts
                               uint4* __restrict__ zp) {   // psum banks (4 bufs)
    int i = blockIdx.x * blockDim.x + threadIdx.x;
    if (i < CVX) {
        float4 v = ((const float4*)x)[i];
        ((uint2*)x_bf)[i] = make_uint2(pack_bf16_rn(v.x, v.y), pack_bf16_rn(v.z, v.w));
    } else if (i < CVX + CN1) {
        int j = i - CVX;
        int n = j / INF_, k = j - n * INF_;
        Wt1[j] = f2bf(W1[(size_t)k * HC_ + n]);
    } else if (i < CVX + CN1 + CN2) {
        int j = i - CVX - CN1;
        int n = j / HC_, k = j - n * HC_;
        Wt2[j] = f2bf(W2[(size_t)k * HC_ + n]);
    } else if (i < CVX + CN1 + CN2 + CN3) {
        int j = i - CVX - CN1 - CN2;
        int n = j / HC_, k = j - n * HC_;
        Wt3[j] = (n < OUTF_) ? f2bf(W3[(size_t)k * OUTF_ + n]) : (ushort_t)0;
    } else if (i < CVX + CN1 + CN2 + CN3 + CZC) {
        zc[i - CVX - CN1 - CN2 - CN3] = make_uint4(0, 0, 0, 0);
    } else if (i < CVX + CN1 + CN2 + CN3 + CZC + CZP) {
        zp[i - CVX - CN1 - CN2 - CN3 - CZC] = make_uint4(0, 0, 0, 0);
    }
}

// ---------------------------------------------------------------------------
// CSR build (by destination)
// ---------------------------------------------------------------------------
__global__ void count_kernel(const int* __restrict__ dst, int* __restrict__ counts, int E) {
    int e = blockIdx.x * blockDim.x + threadIdx.x;
    if (e < E) atomicAdd(&counts[dst[e]], 1);
}

// single-workgroup fused scan (replaces scan1 + scan3b): 1024 threads x 10 elems
__global__ __launch_bounds__(1024) void scan_fused_kernel(const int* __restrict__ counts,
                                                          int* __restrict__ offsets,
                                                          int* __restrict__ cursor, int n) {
    __shared__ int tsum[1024];
    int t = threadIdx.x;
    int base = t * 10;
    int v[10];
    int s = 0;
#pragma unroll
    for (int k = 0; k < 10; ++k) {
        int i = base + k;
        int c = (i < n) ? counts[i] : 0;
        v[k] = s;              // exclusive within-thread prefix
        s += c;
    }
    tsum[t] = s;
    __syncthreads();
    for (int off = 1; off < 1024; off <<= 1) {
        int u = (t >= off) ? tsum[t - off] : 0;
        __syncthreads();
        tsum[t] += u;
        __syncthreads();
    }
    int prefix = (t > 0) ? tsum[t - 1] : 0;
#pragma unroll
    for (int k = 0; k < 10; ++k) {
        int i = base + k;
        if (i < n) {
            int o = prefix + v[k];
            offsets[i] = o;
            cursor[i] = o;
        }
    }
    if (t == 1023) offsets[n] = tsum[1023];
}

__global__ void scatter_kernel(const int* __restrict__ src, const int* __restrict__ dst,
                               int* __restrict__ cursor, int* __restrict__ esrc, int E) {
    int e = blockIdx.x * blockDim.x + threadIdx.x;
    if (e < E) {
        int p = atomicAdd(&cursor[dst[e]], 1);
        esrc[p] = src[e];
    }
}

// ---------------------------------------------------------------------------
// bf16 MFMA GEMM — 64(M) x 128(N) tile, BK=32, plain 2-D grid,
// REGISTER-PREFETCH pipeline (proven 486.6 µs structure).
// ---------------------------------------------------------------------------
#define LDT 40

__global__ __launch_bounds__(256) void gemm_kernel(
    const ushort_t* __restrict__ A,    // [M][K] bf16
    const ushort_t* __restrict__ Bt,   // [512][K] bf16 (transposed, padded)
    ushort_t* __restrict__ Cb,         // [M][512] bf16
    int M, int K)
{
    __shared__ __align__(16) ushort_t As[64 * LDT];
    __shared__ __align__(16) ushort_t Bs[128 * LDT];

    int m0 = blockIdx.y * 64;
    int n0 = blockIdx.x * 128;

    int tid  = threadIdx.x;
    int lane = tid & 63;
    int w    = tid >> 6;
    int wm   = (w & 1) * 32;       // wave m-offset
    int wn   = (w >> 1) * 64;      // wave n-offset
    int quad = lane >> 4;
    int c16  = lane & 15;

    f32x4 acc[2][4];
#pragma unroll
    for (int i = 0; i < 2; ++i)
#pragma unroll
        for (int j = 0; j < 4; ++j)
#pragma unroll
            for (int r = 0; r < 4; ++r) acc[i][j][r] = 0.0f;

    // staging coords
    int sr = tid >> 2;              // A row 0..63
    int sk = (tid & 3) * 8;         // A k-chunk
    int gm = m0 + sr;  if (gm > M - 1) gm = M - 1;
    const ushort_t* aptr = A + (size_t)gm * K + sk;
    int br0 = tid >> 2;             // B rows (2 chunks/thread)
    int bk0 = (tid & 3) * 8;
    int br1 = (256 + tid) >> 2;
    int bk1 = bk0;
    const ushort_t* bptr0 = Bt + (size_t)(n0 + br0) * K + bk0;
    const ushort_t* bptr1 = Bt + (size_t)(n0 + br1) * K + bk1;

    uint4 av  = *(const uint4*)(aptr);
    uint4 bv0 = *(const uint4*)(bptr0);
    uint4 bv1 = *(const uint4*)(bptr1);

    for (int k0 = 0; k0 < K; k0 += 32) {
        *(uint4*)&As[sr * LDT + sk]   = av;
        *(uint4*)&Bs[br0 * LDT + bk0] = bv0;
        *(uint4*)&Bs[br1 * LDT + bk1] = bv1;
        __syncthreads();

        short8x af0 = *(const short8x*)&As[(wm +      c16) * LDT + quad * 8];
        short8x af1 = *(const short8x*)&As[(wm + 16 + c16) * LDT + quad * 8];
        short8x bf[4];
#pragma unroll
        for (int nt = 0; nt < 4; ++nt)
            bf[nt] = *(const short8x*)&Bs[(wn + nt * 16 + c16) * LDT + quad * 8];

        // prefetch next iteration's tiles (in flight across MFMAs + barrier)
        if (k0 + 32 < K) {
            av  = *(const uint4*)(aptr  + k0 + 32);
            bv0 = *(const uint4*)(bptr0 + k0 + 32);
            bv1 = *(const uint4*)(bptr1 + k0 + 32);
        }

#pragma unroll
        for (int nt = 0; nt < 4; ++nt) {
            acc[0][nt] = __builtin_amdgcn_mfma_f32_16x16x32_bf16(af0, bf[nt], acc[0][nt], 0, 0, 0);
            acc[1][nt] = __builtin_amdgcn_mfma_f32_16x16x32_bf16(af1, bf[nt], acc[1][nt], 0, 0, 0);
        }
        __syncthreads();
    }

#pragma unroll
    for (int mt = 0; mt < 2; ++mt) {
#pragma unroll
        for (int r = 0; r < 4; ++r) {
            int row = m0 + wm + mt * 16 + quad * 4 + r;
            if (row < M) {
#pragma unroll
                for (int nt = 0; nt < 4; ++nt) {
                    int col = n0 + wn + nt * 16 + c16;
                    Cb[(size_t)row * 512 + col] = f2bf(acc[mt][nt][r]);
                }
            }
        }
    }
}

// ---------------------------------------------------------------------------
// logits: one wave per node (4 nodes/block). Lane l owns channels [8l, 8l+8).
// ---------------------------------------------------------------------------
template<int H>
__global__ __launch_bounds__(256) void logits_kernel(
    const uint4* __restrict__ xpb4,    // [node][64]
    const float* __restrict__ aS, const float* __restrict__ aD,
    float* __restrict__ s_log, float* __restrict__ d_log, int OUTC)
{
    int node = blockIdx.x * 4 + (threadIdx.x >> 6);
    if (node >= NNODES) return;
    int lane = threadIdx.x & 63;
    uint4 p = xpb4[(size_t)node * 64 + lane];
    float xv[8] = {bf_lo(p.x), bf_hi(p.x), bf_lo(p.y), bf_hi(p.y),
                   bf_lo(p.z), bf_hi(p.z), bf_lo(p.w), bf_hi(p.w)};
    int cbase = lane * 8;
    float sv = 0.f, dv = 0.f;
    if (cbase + 7 < OUTC) {
        float4 a0 = ((const float4*)aS)[lane * 2];
        float4 a1 = ((const float4*)aS)[lane * 2 + 1];
        float4 b0 = ((const float4*)aD)[lane * 2];
        float4 b1 = ((const float4*)aD)[lane * 2 + 1];
        sv = xv[0]*a0.x + xv[1]*a0.y + xv[2]*a0.z + xv[3]*a0.w
           + xv[4]*a1.x + xv[5]*a1.y + xv[6]*a1.z + xv[7]*a1.w;
        dv = xv[0]*b0.x + xv[1]*b0.y + xv[2]*b0.z + xv[3]*b0.w
           + xv[4]*b1.x + xv[5]*b1.y + xv[6]*b1.z + xv[7]*b1.w;
    } else {
#pragma unroll
        for (int k = 0; k < 8; ++k) {
            int c = cbase + k;
            if (c < OUTC) { sv += xv[k] * aS[c]; dv += xv[k] * aD[c]; }
        }
    }
    int grp = (H == 4) ? 16 : 64;
    for (int off = 1; off < grp; off <<= 1) {
        sv += __shfl_xor(sv, off);
        dv += __shfl_xor(dv, off);
    }
    if ((lane & (grp - 1)) == 0) {
        int h = (H == 4) ? (lane >> 4) : 0;
        s_log[node * H + h] = sv;
        d_log[node * H + h] = dv;
    }
}

// ---------------------------------------------------------------------------
// FUSED softmax+gather (+ BN partial stats in epilogue when BN=true).
//   out = (x_self + Σ_j w_j x_{src_j}) / (1 + Σ_j w_j),
//   w_j = exp(lrelu(s[src_j]+d[n]) - c0),  c0 = self logit (shift; w_self=1).
// BN stats: fire-and-forget atomicAdd of v and v^2 into 64-way banked
// partials — removes the bn_stats full-pass kernels.
// ---------------------------------------------------------------------------
__device__ __forceinline__ void acc8(float* acc, uint4 q, float w) {
    acc[0] += w * bf_lo(q.x); acc[1] += w * bf_hi(q.x);
    acc[2] += w * bf_lo(q.y); acc[3] += w * bf_hi(q.y);
    acc[4] += w * bf_lo(q.z); acc[5] += w * bf_hi(q.z);
    acc[6] += w * bf_lo(q.w); acc[7] += w * bf_hi(q.w);
}

template<int H, bool BN>
__global__ __launch_bounds__(256) void gather_fused_kernel(
    const uint4* __restrict__ xpb4,     // [node][64]
    const int* __restrict__ offsets, const int* __restrict__ esrc,
    const float* __restrict__ s_log,    // [node][H]
    const float* __restrict__ d_log,    // [node][H]
    const float* __restrict__ bias,     // [OUTC]
    float* __restrict__ out,            // [node][ldo]
    float* __restrict__ psum,           // [64][512] banked partial sums
    float* __restrict__ psumsq,         // [64][512]
    int OUTC, int ldo)
{
    int id = blockIdx.x;
    int xcd = id & 7;
    int slice = xcd >> 1;                       // 0..3 — pinned per XCD pair
    int sub2 = xcd & 1;
    int wv = threadIdx.x >> 6;
    int node = (id >> 3) * 8 + sub2 * 4 + wv;
    if (node >= NNODES) return;
    int lane = threadIdx.x & 63;
    int esub = lane >> 4;                       // edge subgroup 0..3
    int l16 = lane & 15;
    int h = (H == 4) ? slice : 0;
    int rowoff = slice * 16 + l16;              // uint4 index within 64-wide row

    // node-constant attention terms
    float dh = d_log[node * H + h];
    float c0 = lrelu(s_log[node * H + h] + dh); // self-loop logit = shift

    float acc[8];
    float z;
    if (esub == 0) {
        // self loop: w = exp(c0 - c0) = 1
        uint4 p = xpb4[(size_t)node * 64 + rowoff];
        acc[0] = bf_lo(p.x); acc[1] = bf_hi(p.x);
        acc[2] = bf_lo(p.y); acc[3] = bf_hi(p.y);
        acc[4] = bf_lo(p.z); acc[5] = bf_hi(p.z);
        acc[6] = bf_lo(p.w); acc[7] = bf_hi(p.w);
        z = 1.0f;
    } else {
#pragma unroll
        for (int k = 0; k < 8; ++k) acc[k] = 0.f;
        z = 0.f;
    }

    int e0 = offsets[node], e1 = offsets[node + 1];
    int j = e0 + esub;
    for (; j + 12 < e1; j += 16) {
        int s0 = esrc[j], s1 = esrc[j + 4], s2 = esrc[j + 8], s3 = esrc[j + 12];
        uint4 q0 = xpb4[(size_t)s0 * 64 + rowoff];
        uint4 q1 = xpb4[(size_t)s1 * 64 + rowoff];
        uint4 q2 = xpb4[(size_t)s2 * 64 + rowoff];
        uint4 q3 = xpb4[(size_t)s3 * 64 + rowoff];
        float w0 = __expf(lrelu(s_log[s0 * H + h] + dh) - c0);
        float w1 = __expf(lrelu(s_log[s1 * H + h] + dh) - c0);
        float w2 = __expf(lrelu(s_log[s2 * H + h] + dh) - c0);
        float w3 = __expf(lrelu(s_log[s3 * H + h] + dh) - c0);
        acc8(acc, q0, w0);
        acc8(acc, q1, w1);
        acc8(acc, q2, w2);
        acc8(acc, q3, w3);
        z += w0 + w1 + w2 + w3;
    }
    for (; j < e1; j += 4) {
        int s0 = esrc[j];
        uint4 q0 = xpb4[(size_t)s0 * 64 + rowoff];
        float w0 = __expf(lrelu(s_log[s0 * H + h] + dh) - c0);
        acc8(acc, q0, w0);
        z += w0;
    }

    // combine the 4 edge subgroups
#pragma unroll
    for (int k = 0; k < 8; ++k) {
        acc[k] += __shfl_xor(acc[k], 16);
        acc[k] += __shfl_xor(acc[k], 32);
    }
    z += __shfl_xor(z, 16);
    z += __shfl_xor(z, 32);

    if (esub == 0) {
        float zi = 1.0f / z;
        int cbase = slice * 128 + l16 * 8;
        size_t ob = (size_t)node * ldo + cbase;
        float v[8];
#pragma unroll
        for (int k = 0; k < 8; ++k) v[k] = acc[k] * zi + bias[cbase + k];
        if (cbase + 7 < OUTC) {
            *(float4*)(out + ob)     = make_float4(v[0], v[1], v[2], v[3]);
            *(float4*)(out + ob + 4) = make_float4(v[4], v[5], v[6], v[7]);
        } else {
#pragma unroll
            for (int k = 0; k < 8; ++k) {
                int c = cbase + k;
                if (c < OUTC) out[ob + k] = v[k];
            }
        }
        if (BN) {
            int bank = (id >> 3) & 63;
            float* ps  = psum   + (size_t)bank * 512 + cbase;
            float* psq = psumsq + (size_t)bank * 512 + cbase;
#pragma unroll
            for (int k = 0; k < 8; ++k) {
                atomicAdd(&ps[k], v[k]);
                atomicAdd(&psq[k], v[k] * v[k]);
            }
        }
    }
}

// ---------------------------------------------------------------------------
// BatchNorm apply (+ inline finalize of the 64-bank partials) + ELU + pack.
// ---------------------------------------------------------------------------
__global__ __launch_bounds__(256) void bn_apply_kernel(const float* __restrict__ h,
                                                       const float* __restrict__ psum,
                                                       const float* __restrict__ psumsq,
                                                       const float* __restrict__ gamma,
                                                       const float* __restrict__ beta,
                                                       uint_t* __restrict__ hbf) {
    int t = threadIdx.x, b = blockIdx.x;   // grid = 256
    int c0 = t * 2, c1 = c0 + 1;
    // inline finalize: reduce 64 banks for this thread's two channels
    float sm0 = 0.f, sq0 = 0.f, sm1 = 0.f, sq1 = 0.f;
    for (int k = 0; k < 64; ++k) {
        sm0 += psum[k * 512 + c0];   sq0 += psumsq[k * 512 + c0];
        sm1 += psum[k * 512 + c1];   sq1 += psumsq[k * 512 + c1];
    }
    const float invN = 1.0f / (float)NNODES;
    float mu0 = sm0 * invN, mu1 = sm1 * invN;
    float var0 = sq0 * invN - mu0 * mu0;
    float var1 = sq1 * invN - mu1 * mu1;
    float sc0 = gamma[c0] * rsqrtf(var0 + BN_EPS);
    float sc1 = gamma[c1] * rsqrtf(var1 + BN_EPS);
    float sh0 = beta[c0] - mu0 * sc0;
    float sh1 = beta[c1] - mu1 * sc1;
    for (int r = b; r < NNODES; r += 256) {
        float2 hv = ((const float2*)(h + (size_t)r * 512))[t];
        float v0 = hv.x * sc0 + sh0;
        float v1 = hv.y * sc1 + sh1;
        v0 = (v0 > 0.f) ? v0 : (__expf(v0) - 1.0f);
        v1 = (v1 > 0.f) ? v1 : (__expf(v1) - 1.0f);
        hbf[r * 256 + t] = ((uint_t)f2bf(v1) << 16) | (uint_t)f2bf(v0);
    }
}

// ---------------------------------------------------------------------------
// launch — 15 dispatches
// ---------------------------------------------------------------------------
extern "C" void kernel_launch(void* const* d_in, const int* in_sizes, int n_in,
                              void* d_out, int out_size, void* d_ws, size_t ws_size,
                              hipStream_t stream) {
    const float* x      = (const float*)d_in[0];
    const int*   ei     = (const int*)d_in[1];
    const float* W1     = (const float*)d_in[2];
    const float* a_src1 = (const float*)d_in[3];
    const float* a_dst1 = (const float*)d_in[4];
    const float* b1     = (const float*)d_in[5];
    const float* g1     = (const float*)d_in[6];
    const float* be1    = (const float*)d_in[7];
    const float* W2     = (const float*)d_in[8];
    const float* a_src2 = (const float*)d_in[9];
    const float* a_dst2 = (const float*)d_in[10];
    const float* b2     = (const float*)d_in[11];
    const float* g2     = (const float*)d_in[12];
    const float* be2    = (const float*)d_in[13];
    const float* W3     = (const float*)d_in[14];
    const float* a_src3 = (const float*)d_in[15];
    const float* a_dst3 = (const float*)d_in[16];
    const float* b3     = (const float*)d_in[17];
    float* out = (float*)d_out;

    const int* e_src = ei;           // edge_index[0]
    const int* e_dst = ei + NEDGES;  // edge_index[1]

    // ---- workspace layout ----
    char* w = (char*)d_ws;
    ushort_t* x_bf = (ushort_t*)w;
    float*    hbuf = (float*)w;                               // alias after L1 GEMM
    w += (size_t)NNODES * INF_ * sizeof(ushort_t);            // 25.6 MB
    uint_t* xpb = (uint_t*)w;  w += (size_t)NNODES * HC_ * sizeof(ushort_t);
    uint_t* hbf = (uint_t*)w;  w += (size_t)NNODES * HC_ * sizeof(ushort_t);
    ushort_t* Wt1 = (ushort_t*)w; w += (size_t)HC_ * INF_ * sizeof(ushort_t);
    ushort_t* Wt2 = (ushort_t*)w; w += (size_t)HC_ * HC_ * sizeof(ushort_t);
    ushort_t* Wt3 = (ushort_t*)w; w += (size_t)HC_ * HC_ * sizeof(ushort_t);
    int* counts  = (int*)w;    w += NNODES * sizeof(int);
    float* s_log = (float*)w;  w += NNODES * HEADS_ * sizeof(float);
    float* d_log = (float*)w;  w += NNODES * HEADS_ * sizeof(float);
    float* psumall = (float*)w; w += (size_t)4 * 64 * HC_ * sizeof(float);  // 524 KB
    int* offsets = (int*)w;    w += (NNODES + 1) * sizeof(int);
    int* cursor  = (int*)w;    w += NNODES * sizeof(int);
    int* esrc    = (int*)w;    w += NEDGES * sizeof(int);

    float* psum1   = psumall;
    float* psumsq1 = psumall + 64 * HC_;
    float* psum2   = psumall + 2 * 64 * HC_;
    float* psumsq2 = psumall + 3 * 64 * HC_;

    dim3 gg(HC_ / 128, (NNODES + 63) / 64);          // (4, 157) — 64x128 tile
    const int lgGrid = (NNODES + 3) / 4;             // 2500 (logits)
    const int gaGrid = ((NNODES + 7) / 8) * 8;       // 10000 (sliced gather)

    {
        int TOT = CVX + CN1 + CN2 + CN3 + CZC + CZP;
        convall_kernel<<<(TOT + 255) / 256, 256, 0, stream>>>(x, W1, W2, W3,
            x_bf, Wt1, Wt2, Wt3, (uint4*)counts, (uint4*)psumall);
    }
    count_kernel<<<(NEDGES + 255) / 256, 256, 0, stream>>>(e_dst, counts, NEDGES);
    scan_fused_kernel<<<1, 1024, 0, stream>>>(counts, offsets, cursor, NNODES);
    scatter_kernel<<<(NEDGES + 255) / 256, 256, 0, stream>>>(e_src, e_dst, cursor, esrc, NEDGES);

    // ---- Layer 1 ----
    gemm_kernel<<<gg, 256, 0, stream>>>(x_bf, Wt1, (ushort_t*)xpb, NNODES, INF_);
    logits_kernel<HEADS_><<<lgGrid, 256, 0, stream>>>((const uint4*)xpb, a_src1, a_dst1, s_log, d_log, HC_);
    gather_fused_kernel<HEADS_, true><<<gaGrid, 256, 0, stream>>>((const uint4*)xpb, offsets, esrc,
        s_log, d_log, b1, hbuf, psum1, psumsq1, HC_, HC_);
    bn_apply_kernel<<<256, 256, 0, stream>>>(hbuf, psum1, psumsq1, g1, be1, hbf);

    // ---- Layer 2 ----
    gemm_kernel<<<gg, 256, 0, stream>>>((const ushort_t*)hbf, Wt2, (ushort_t*)xpb, NNODES, HC_);
    logits_kernel<HEADS_><<<lgGrid, 256, 0, stream>>>((const uint4*)xpb, a_src2, a_dst2, s_log, d_log, HC_);
    gather_fused_kernel<HEADS_, true><<<gaGrid, 256, 0, stream>>>((const uint4*)xpb, offsets, esrc,
        s_log, d_log, b2, hbuf, psum2, psumsq2, HC_, HC_);
    bn_apply_kernel<<<256, 256, 0, stream>>>(hbuf, psum2, psumsq2, g2, be2, hbf);

    // ---- Layer 3 (H=1, N=500) ----
    gemm_kernel<<<gg, 256, 0, stream>>>((const ushort_t*)hbf, Wt3, (ushort_t*)xpb, NNODES, HC_);
    logits_kernel<1><<<lgGrid, 256, 0, stream>>>((const uint4*)xpb, a_src3, a_dst3, s_log, d_log, OUTF_);
    gather_fused_kernel<1, false><<<gaGrid, 256, 0, stream>>>((const uint4*)xpb, offsets, esrc,
        s_log, d_log, b3, out, nullptr, nullptr, OUTF_, OUTF_);
}

// Round 5
// 470.592 us; speedup vs baseline: 1.9313x; 1.9313x over previous
//
#include <hip/hip_runtime.h>
#include <hip/hip_bf16.h>

// Problem constants (from reference)
#define NNODES 10000
#define NEDGES 320000
#define INF_   1280
#define HID_   128
#define HEADS_ 4
#define OUTF_  500
#define HC_    512          // HEADS_*HID_
#define NEG_SLOPE 0.2f
#define BN_EPS 1e-5f

typedef __attribute__((ext_vector_type(8))) short short8x;
typedef __attribute__((ext_vector_type(4))) float f32x4;
typedef unsigned short ushort_t;
typedef unsigned int uint_t;

__device__ __forceinline__ ushort_t f2bf(float f) {
    uint_t u = __float_as_uint(f);
    u = (u + 0x7fffu + ((u >> 16) & 1u)) >> 16;   // round-to-nearest-even
    return (ushort_t)u;
}
__device__ __forceinline__ float bf_lo(uint_t p) { return __uint_as_float(p << 16); }
__device__ __forceinline__ float bf_hi(uint_t p) { return __uint_as_float(p & 0xffff0000u); }
__device__ __forceinline__ float lrelu(float x) { return (x >= 0.f) ? x : NEG_SLOPE * x; }
__device__ __forceinline__ uint_t pack_bf16_rn(float a, float b) {
    __hip_bfloat162 h = __float22bfloat162_rn(make_float2(a, b));  // hw packed cvt, RNE
    return *(uint_t*)&h;
}

// ---------------------------------------------------------------------------
// convall: x->bf16 + 3 weight transposes + zero counts.
// NOTE (R3 lesson): do NOT fuse BN-stats atomics into gather — cross-XCD
// shared-line atomicAdds bypass L2 (non-coherent per-XCD L2) and become
// ~32B HBM transactions each: 10M atomics => 340MB WRITE_SIZE, 297µs.
// ---------------------------------------------------------------------------
#define CVX (NNODES * INF_ / 4)        // 3,200,000 float4 chunks of x
#define CN1 (HC_ * INF_)
#define CN2 (HC_ * HC_)
#define CN3 (HC_ * HC_)                // Wt3 (padded rows)
#define CZC (NNODES / 4)               // counts as uint4 (10000 ints = 2500)
__global__ void convall_kernel(const float* __restrict__ x,
                               const float* __restrict__ W1,
                               const float* __restrict__ W2,
                               const float* __restrict__ W3,
                               ushort_t* __restrict__ x_bf,
                               ushort_t* __restrict__ Wt1,
                               ushort_t* __restrict__ Wt2,
                               ushort_t* __restrict__ Wt3,
                               uint4* __restrict__ zc) {   // counts
    int i = blockIdx.x * blockDim.x + threadIdx.x;
    if (i < CVX) {
        float4 v = ((const float4*)x)[i];
        ((uint2*)x_bf)[i] = make_uint2(pack_bf16_rn(v.x, v.y), pack_bf16_rn(v.z, v.w));
    } else if (i < CVX + CN1) {
        int j = i - CVX;
        int n = j / INF_, k = j - n * INF_;
        Wt1[j] = f2bf(W1[(size_t)k * HC_ + n]);
    } else if (i < CVX + CN1 + CN2) {
        int j = i - CVX - CN1;
        int n = j / HC_, k = j - n * HC_;
        Wt2[j] = f2bf(W2[(size_t)k * HC_ + n]);
    } else if (i < CVX + CN1 + CN2 + CN3) {
        int j = i - CVX - CN1 - CN2;
        int n = j / HC_, k = j - n * HC_;
        Wt3[j] = (n < OUTF_) ? f2bf(W3[(size_t)k * OUTF_ + n]) : (ushort_t)0;
    } else if (i < CVX + CN1 + CN2 + CN3 + CZC) {
        zc[i - CVX - CN1 - CN2 - CN3] = make_uint4(0, 0, 0, 0);
    }
}

// ---------------------------------------------------------------------------
// CSR build (by destination)
// ---------------------------------------------------------------------------
__global__ void count_kernel(const int* __restrict__ dst, int* __restrict__ counts, int E) {
    int e = blockIdx.x * blockDim.x + threadIdx.x;
    if (e < E) atomicAdd(&counts[dst[e]], 1);
}

// single-workgroup fused scan (replaces scan1 + scan3b): 1024 threads x 10 elems
__global__ __launch_bounds__(1024) void scan_fused_kernel(const int* __restrict__ counts,
                                                          int* __restrict__ offsets,
                                                          int* __restrict__ cursor, int n) {
    __shared__ int tsum[1024];
    int t = threadIdx.x;
    int base = t * 10;
    int v[10];
    int s = 0;
#pragma unroll
    for (int k = 0; k < 10; ++k) {
        int i = base + k;
        int c = (i < n) ? counts[i] : 0;
        v[k] = s;              // exclusive within-thread prefix
        s += c;
    }
    tsum[t] = s;
    __syncthreads();
    for (int off = 1; off < 1024; off <<= 1) {
        int u = (t >= off) ? tsum[t - off] : 0;
        __syncthreads();
        tsum[t] += u;
        __syncthreads();
    }
    int prefix = (t > 0) ? tsum[t - 1] : 0;
#pragma unroll
    for (int k = 0; k < 10; ++k) {
        int i = base + k;
        if (i < n) {
            int o = prefix + v[k];
            offsets[i] = o;
            cursor[i] = o;
        }
    }
    if (t == 1023) offsets[n] = tsum[1023];
}

__global__ void scatter_kernel(const int* __restrict__ src, const int* __restrict__ dst,
                               int* __restrict__ cursor, int* __restrict__ esrc, int E) {
    int e = blockIdx.x * blockDim.x + threadIdx.x;
    if (e < E) {
        int p = atomicAdd(&cursor[dst[e]], 1);
        esrc[p] = src[e];
    }
}

// ---------------------------------------------------------------------------
// bf16 MFMA GEMM — 64(M) x 128(N) tile, BK=32, plain 2-D grid,
// REGISTER-PREFETCH pipeline (proven 486.6 µs structure).
// ---------------------------------------------------------------------------
#define LDT 40

__global__ __launch_bounds__(256) void gemm_kernel(
    const ushort_t* __restrict__ A,    // [M][K] bf16
    const ushort_t* __restrict__ Bt,   // [512][K] bf16 (transposed, padded)
    ushort_t* __restrict__ Cb,         // [M][512] bf16
    int M, int K)
{
    __shared__ __align__(16) ushort_t As[64 * LDT];
    __shared__ __align__(16) ushort_t Bs[128 * LDT];

    int m0 = blockIdx.y * 64;
    int n0 = blockIdx.x * 128;

    int tid  = threadIdx.x;
    int lane = tid & 63;
    int w    = tid >> 6;
    int wm   = (w & 1) * 32;       // wave m-offset
    int wn   = (w >> 1) * 64;      // wave n-offset
    int quad = lane >> 4;
    int c16  = lane & 15;

    f32x4 acc[2][4];
#pragma unroll
    for (int i = 0; i < 2; ++i)
#pragma unroll
        for (int j = 0; j < 4; ++j)
#pragma unroll
            for (int r = 0; r < 4; ++r) acc[i][j][r] = 0.0f;

    // staging coords
    int sr = tid >> 2;              // A row 0..63
    int sk = (tid & 3) * 8;         // A k-chunk
    int gm = m0 + sr;  if (gm > M - 1) gm = M - 1;
    const ushort_t* aptr = A + (size_t)gm * K + sk;
    int br0 = tid >> 2;             // B rows (2 chunks/thread)
    int bk0 = (tid & 3) * 8;
    int br1 = (256 + tid) >> 2;
    int bk1 = bk0;
    const ushort_t* bptr0 = Bt + (size_t)(n0 + br0) * K + bk0;
    const ushort_t* bptr1 = Bt + (size_t)(n0 + br1) * K + bk1;

    uint4 av  = *(const uint4*)(aptr);
    uint4 bv0 = *(const uint4*)(bptr0);
    uint4 bv1 = *(const uint4*)(bptr1);

    for (int k0 = 0; k0 < K; k0 += 32) {
        *(uint4*)&As[sr * LDT + sk]   = av;
        *(uint4*)&Bs[br0 * LDT + bk0] = bv0;
        *(uint4*)&Bs[br1 * LDT + bk1] = bv1;
        __syncthreads();

        short8x af0 = *(const short8x*)&As[(wm +      c16) * LDT + quad * 8];
        short8x af1 = *(const short8x*)&As[(wm + 16 + c16) * LDT + quad * 8];
        short8x bf[4];
#pragma unroll
        for (int nt = 0; nt < 4; ++nt)
            bf[nt] = *(const short8x*)&Bs[(wn + nt * 16 + c16) * LDT + quad * 8];

        // prefetch next iteration's tiles (in flight across MFMAs + barrier)
        if (k0 + 32 < K) {
            av  = *(const uint4*)(aptr  + k0 + 32);
            bv0 = *(const uint4*)(bptr0 + k0 + 32);
            bv1 = *(const uint4*)(bptr1 + k0 + 32);
        }

#pragma unroll
        for (int nt = 0; nt < 4; ++nt) {
            acc[0][nt] = __builtin_amdgcn_mfma_f32_16x16x32_bf16(af0, bf[nt], acc[0][nt], 0, 0, 0);
            acc[1][nt] = __builtin_amdgcn_mfma_f32_16x16x32_bf16(af1, bf[nt], acc[1][nt], 0, 0, 0);
        }
        __syncthreads();
    }

#pragma unroll
    for (int mt = 0; mt < 2; ++mt) {
#pragma unroll
        for (int r = 0; r < 4; ++r) {
            int row = m0 + wm + mt * 16 + quad * 4 + r;
            if (row < M) {
#pragma unroll
                for (int nt = 0; nt < 4; ++nt) {
                    int col = n0 + wn + nt * 16 + c16;
                    Cb[(size_t)row * 512 + col] = f2bf(acc[mt][nt][r]);
                }
            }
        }
    }
}

// ---------------------------------------------------------------------------
// logits: one wave per node (4 nodes/block). Lane l owns channels [8l, 8l+8).
// ---------------------------------------------------------------------------
template<int H>
__global__ __launch_bounds__(256) void logits_kernel(
    const uint4* __restrict__ xpb4,    // [node][64]
    const float* __restrict__ aS, const float* __restrict__ aD,
    float* __restrict__ s_log, float* __restrict__ d_log, int OUTC)
{
    int node = blockIdx.x * 4 + (threadIdx.x >> 6);
    if (node >= NNODES) return;
    int lane = threadIdx.x & 63;
    uint4 p = xpb4[(size_t)node * 64 + lane];
    float xv[8] = {bf_lo(p.x), bf_hi(p.x), bf_lo(p.y), bf_hi(p.y),
                   bf_lo(p.z), bf_hi(p.z), bf_lo(p.w), bf_hi(p.w)};
    int cbase = lane * 8;
    float sv = 0.f, dv = 0.f;
    if (cbase + 7 < OUTC) {
        float4 a0 = ((const float4*)aS)[lane * 2];
        float4 a1 = ((const float4*)aS)[lane * 2 + 1];
        float4 b0 = ((const float4*)aD)[lane * 2];
        float4 b1 = ((const float4*)aD)[lane * 2 + 1];
        sv = xv[0]*a0.x + xv[1]*a0.y + xv[2]*a0.z + xv[3]*a0.w
           + xv[4]*a1.x + xv[5]*a1.y + xv[6]*a1.z + xv[7]*a1.w;
        dv = xv[0]*b0.x + xv[1]*b0.y + xv[2]*b0.z + xv[3]*b0.w
           + xv[4]*b1.x + xv[5]*b1.y + xv[6]*b1.z + xv[7]*b1.w;
    } else {
#pragma unroll
        for (int k = 0; k < 8; ++k) {
            int c = cbase + k;
            if (c < OUTC) { sv += xv[k] * aS[c]; dv += xv[k] * aD[c]; }
        }
    }
    int grp = (H == 4) ? 16 : 64;
    for (int off = 1; off < grp; off <<= 1) {
        sv += __shfl_xor(sv, off);
        dv += __shfl_xor(dv, off);
    }
    if ((lane & (grp - 1)) == 0) {
        int h = (H == 4) ? (lane >> 4) : 0;
        s_log[node * H + h] = sv;
        d_log[node * H + h] = dv;
    }
}

// ---------------------------------------------------------------------------
// FUSED softmax+gather (no BN epilogue — see R3 lesson above).
//   out = (x_self + Σ_j w_j x_{src_j}) / (1 + Σ_j w_j),
//   w_j = exp(lrelu(s[src_j]+d[n]) - c0),  c0 = self logit (shift; w_self=1).
// Slicing (proven): slice pinned per XCD pair, 2.56 MB L2-resident.
// ---------------------------------------------------------------------------
__device__ __forceinline__ void acc8(float* acc, uint4 q, float w) {
    acc[0] += w * bf_lo(q.x); acc[1] += w * bf_hi(q.x);
    acc[2] += w * bf_lo(q.y); acc[3] += w * bf_hi(q.y);
    acc[4] += w * bf_lo(q.z); acc[5] += w * bf_hi(q.z);
    acc[6] += w * bf_lo(q.w); acc[7] += w * bf_hi(q.w);
}

template<int H>
__global__ __launch_bounds__(256) void gather_fused_kernel(
    const uint4* __restrict__ xpb4,     // [node][64]
    const int* __restrict__ offsets, const int* __restrict__ esrc,
    const float* __restrict__ s_log,    // [node][H]
    const float* __restrict__ d_log,    // [node][H]
    const float* __restrict__ bias,     // [OUTC]
    float* __restrict__ out,            // [node][ldo]
    int OUTC, int ldo)
{
    int id = blockIdx.x;
    int xcd = id & 7;
    int slice = xcd >> 1;                       // 0..3 — pinned per XCD pair
    int sub2 = xcd & 1;
    int wv = threadIdx.x >> 6;
    int node = (id >> 3) * 8 + sub2 * 4 + wv;
    if (node >= NNODES) return;
    int lane = threadIdx.x & 63;
    int esub = lane >> 4;                       // edge subgroup 0..3
    int l16 = lane & 15;
    int h = (H == 4) ? slice : 0;
    int rowoff = slice * 16 + l16;              // uint4 index within 64-wide row

    // node-constant attention terms
    float dh = d_log[node * H + h];
    float c0 = lrelu(s_log[node * H + h] + dh); // self-loop logit = shift

    float acc[8];
    float z;
    if (esub == 0) {
        // self loop: w = exp(c0 - c0) = 1
        uint4 p = xpb4[(size_t)node * 64 + rowoff];
        acc[0] = bf_lo(p.x); acc[1] = bf_hi(p.x);
        acc[2] = bf_lo(p.y); acc[3] = bf_hi(p.y);
        acc[4] = bf_lo(p.z); acc[5] = bf_hi(p.z);
        acc[6] = bf_lo(p.w); acc[7] = bf_hi(p.w);
        z = 1.0f;
    } else {
#pragma unroll
        for (int k = 0; k < 8; ++k) acc[k] = 0.f;
        z = 0.f;
    }

    int e0 = offsets[node], e1 = offsets[node + 1];
    int j = e0 + esub;
    for (; j + 12 < e1; j += 16) {
        int s0 = esrc[j], s1 = esrc[j + 4], s2 = esrc[j + 8], s3 = esrc[j + 12];
        uint4 q0 = xpb4[(size_t)s0 * 64 + rowoff];
        uint4 q1 = xpb4[(size_t)s1 * 64 + rowoff];
        uint4 q2 = xpb4[(size_t)s2 * 64 + rowoff];
        uint4 q3 = xpb4[(size_t)s3 * 64 + rowoff];
        float w0 = __expf(lrelu(s_log[s0 * H + h] + dh) - c0);
        float w1 = __expf(lrelu(s_log[s1 * H + h] + dh) - c0);
        float w2 = __expf(lrelu(s_log[s2 * H + h] + dh) - c0);
        float w3 = __expf(lrelu(s_log[s3 * H + h] + dh) - c0);
        acc8(acc, q0, w0);
        acc8(acc, q1, w1);
        acc8(acc, q2, w2);
        acc8(acc, q3, w3);
        z += w0 + w1 + w2 + w3;
    }
    for (; j < e1; j += 4) {
        int s0 = esrc[j];
        uint4 q0 = xpb4[(size_t)s0 * 64 + rowoff];
        float w0 = __expf(lrelu(s_log[s0 * H + h] + dh) - c0);
        acc8(acc, q0, w0);
        z += w0;
    }

    // combine the 4 edge subgroups
#pragma unroll
    for (int k = 0; k < 8; ++k) {
        acc[k] += __shfl_xor(acc[k], 16);
        acc[k] += __shfl_xor(acc[k], 32);
    }
    z += __shfl_xor(z, 16);
    z += __shfl_xor(z, 32);

    if (esub == 0) {
        float zi = 1.0f / z;
        int cbase = slice * 128 + l16 * 8;
        size_t ob = (size_t)node * ldo + cbase;
        if (cbase + 7 < OUTC) {
            float4 o0 = make_float4(acc[0] * zi + bias[cbase + 0], acc[1] * zi + bias[cbase + 1],
                                    acc[2] * zi + bias[cbase + 2], acc[3] * zi + bias[cbase + 3]);
            float4 o1 = make_float4(acc[4] * zi + bias[cbase + 4], acc[5] * zi + bias[cbase + 5],
                                    acc[6] * zi + bias[cbase + 6], acc[7] * zi + bias[cbase + 7]);
            *(float4*)(out + ob) = o0;
            *(float4*)(out + ob + 4) = o1;
        } else {
#pragma unroll
            for (int k = 0; k < 8; ++k) {
                int c = cbase + k;
                if (c < OUTC) out[ob + k] = acc[k] * zi + bias[c];
            }
        }
    }
}

// ---------------------------------------------------------------------------
// BatchNorm: stats (64-block partials, plain writes) -> apply w/ inline
// finalize (each thread reduces its 2 channels' 64 banks; L2-resident).
// ---------------------------------------------------------------------------
__global__ __launch_bounds__(512) void bn_stats_kernel(const float* __restrict__ h,
                                                       float* __restrict__ psum,
                                                       float* __restrict__ psumsq) {
    int c = threadIdx.x;  // 512
    int b = blockIdx.x;   // 64
    float sm = 0.f, sq = 0.f;
    for (int r = b; r < NNODES; r += 64) {
        float v = h[(size_t)r * 512 + c];
        sm += v;
        sq += v * v;
    }
    psum[b * 512 + c] = sm;
    psumsq[b * 512 + c] = sq;
}

__global__ __launch_bounds__(256) void bn_apply_kernel(const float* __restrict__ h,
                                                       const float* __restrict__ psum,
                                                       const float* __restrict__ psumsq,
                                                       const float* __restrict__ gamma,
                                                       const float* __restrict__ beta,
                                                       uint_t* __restrict__ hbf) {
    int t = threadIdx.x, b = blockIdx.x;   // grid = 256
    int c0 = t * 2, c1 = c0 + 1;
    // inline finalize: reduce 64 banks for this thread's two channels
    float sm0 = 0.f, sq0 = 0.f, sm1 = 0.f, sq1 = 0.f;
    for (int k = 0; k < 64; ++k) {
        sm0 += psum[k * 512 + c0];   sq0 += psumsq[k * 512 + c0];
        sm1 += psum[k * 512 + c1];   sq1 += psumsq[k * 512 + c1];
    }
    const float invN = 1.0f / (float)NNODES;
    float mu0 = sm0 * invN, mu1 = sm1 * invN;
    float var0 = sq0 * invN - mu0 * mu0;
    float var1 = sq1 * invN - mu1 * mu1;
    float sc0 = gamma[c0] * rsqrtf(var0 + BN_EPS);
    float sc1 = gamma[c1] * rsqrtf(var1 + BN_EPS);
    float sh0 = beta[c0] - mu0 * sc0;
    float sh1 = beta[c1] - mu1 * sc1;
    for (int r = b; r < NNODES; r += 256) {
        float2 hv = ((const float2*)(h + (size_t)r * 512))[t];
        float v0 = hv.x * sc0 + sh0;
        float v1 = hv.y * sc1 + sh1;
        v0 = (v0 > 0.f) ? v0 : (__expf(v0) - 1.0f);
        v1 = (v1 > 0.f) ? v1 : (__expf(v1) - 1.0f);
        hbf[r * 256 + t] = ((uint_t)f2bf(v1) << 16) | (uint_t)f2bf(v0);
    }
}

// ---------------------------------------------------------------------------
// launch — 17 dispatches
// ---------------------------------------------------------------------------
extern "C" void kernel_launch(void* const* d_in, const int* in_sizes, int n_in,
                              void* d_out, int out_size, void* d_ws, size_t ws_size,
                              hipStream_t stream) {
    const float* x      = (const float*)d_in[0];
    const int*   ei     = (const int*)d_in[1];
    const float* W1     = (const float*)d_in[2];
    const float* a_src1 = (const float*)d_in[3];
    const float* a_dst1 = (const float*)d_in[4];
    const float* b1     = (const float*)d_in[5];
    const float* g1     = (const float*)d_in[6];
    const float* be1    = (const float*)d_in[7];
    const float* W2     = (const float*)d_in[8];
    const float* a_src2 = (const float*)d_in[9];
    const float* a_dst2 = (const float*)d_in[10];
    const float* b2     = (const float*)d_in[11];
    const float* g2     = (const float*)d_in[12];
    const float* be2    = (const float*)d_in[13];
    const float* W3     = (const float*)d_in[14];
    const float* a_src3 = (const float*)d_in[15];
    const float* a_dst3 = (const float*)d_in[16];
    const float* b3     = (const float*)d_in[17];
    float* out = (float*)d_out;

    const int* e_src = ei;           // edge_index[0]
    const int* e_dst = ei + NEDGES;  // edge_index[1]

    // ---- workspace layout ----
    char* w = (char*)d_ws;
    ushort_t* x_bf = (ushort_t*)w;
    float*    hbuf = (float*)w;                               // alias after L1 GEMM
    w += (size_t)NNODES * INF_ * sizeof(ushort_t);            // 25.6 MB
    uint_t* xpb = (uint_t*)w;  w += (size_t)NNODES * HC_ * sizeof(ushort_t);
    uint_t* hbf = (uint_t*)w;  w += (size_t)NNODES * HC_ * sizeof(ushort_t);
    ushort_t* Wt1 = (ushort_t*)w; w += (size_t)HC_ * INF_ * sizeof(ushort_t);
    ushort_t* Wt2 = (ushort_t*)w; w += (size_t)HC_ * HC_ * sizeof(ushort_t);
    ushort_t* Wt3 = (ushort_t*)w; w += (size_t)HC_ * HC_ * sizeof(ushort_t);
    int* counts  = (int*)w;    w += NNODES * sizeof(int);
    float* s_log = (float*)w;  w += NNODES * HEADS_ * sizeof(float);
    float* d_log = (float*)w;  w += NNODES * HEADS_ * sizeof(float);
    float* psum  = (float*)w;  w += 64 * HC_ * sizeof(float);
    float* psumsq= (float*)w;  w += 64 * HC_ * sizeof(float);
    int* offsets = (int*)w;    w += (NNODES + 1) * sizeof(int);
    int* cursor  = (int*)w;    w += NNODES * sizeof(int);
    int* esrc    = (int*)w;    w += NEDGES * sizeof(int);

    dim3 gg(HC_ / 128, (NNODES + 63) / 64);          // (4, 157) — 64x128 tile
    const int lgGrid = (NNODES + 3) / 4;             // 2500 (logits)
    const int gaGrid = ((NNODES + 7) / 8) * 8;       // 10000 (sliced gather)

    {
        int TOT = CVX + CN1 + CN2 + CN3 + CZC;
        convall_kernel<<<(TOT + 255) / 256, 256, 0, stream>>>(x, W1, W2, W3,
            x_bf, Wt1, Wt2, Wt3, (uint4*)counts);
    }
    count_kernel<<<(NEDGES + 255) / 256, 256, 0, stream>>>(e_dst, counts, NEDGES);
    scan_fused_kernel<<<1, 1024, 0, stream>>>(counts, offsets, cursor, NNODES);
    scatter_kernel<<<(NEDGES + 255) / 256, 256, 0, stream>>>(e_src, e_dst, cursor, esrc, NEDGES);

    // ---- Layer 1 ----
    gemm_kernel<<<gg, 256, 0, stream>>>(x_bf, Wt1, (ushort_t*)xpb, NNODES, INF_);
    logits_kernel<HEADS_><<<lgGrid, 256, 0, stream>>>((const uint4*)xpb, a_src1, a_dst1, s_log, d_log, HC_);
    gather_fused_kernel<HEADS_><<<gaGrid, 256, 0, stream>>>((const uint4*)xpb, offsets, esrc,
        s_log, d_log, b1, hbuf, HC_, HC_);
    bn_stats_kernel<<<64, 512, 0, stream>>>(hbuf, psum, psumsq);
    bn_apply_kernel<<<256, 256, 0, stream>>>(hbuf, psum, psumsq, g1, be1, hbf);

    // ---- Layer 2 ----
    gemm_kernel<<<gg, 256, 0, stream>>>((const ushort_t*)hbf, Wt2, (ushort_t*)xpb, NNODES, HC_);
    logits_kernel<HEADS_><<<lgGrid, 256, 0, stream>>>((const uint4*)xpb, a_src2, a_dst2, s_log, d_log, HC_);
    gather_fused_kernel<HEADS_><<<gaGrid, 256, 0, stream>>>((const uint4*)xpb, offsets, esrc,
        s_log, d_log, b2, hbuf, HC_, HC_);
    bn_stats_kernel<<<64, 512, 0, stream>>>(hbuf, psum, psumsq);
    bn_apply_kernel<<<256, 256, 0, stream>>>(hbuf, psum, psumsq, g2, be2, hbf);

    // ---- Layer 3 (H=1, N=500) ----
    gemm_kernel<<<gg, 256, 0, stream>>>((const ushort_t*)hbf, Wt3, (ushort_t*)xpb, NNODES, HC_);
    logits_kernel<1><<<lgGrid, 256, 0, stream>>>((const uint4*)xpb, a_src3, a_dst3, s_log, d_log, OUTF_);
    gather_fused_kernel<1><<<gaGrid, 256, 0, stream>>>((const uint4*)xpb, offsets, esrc,
        s_log, d_log, b3, out, OUTF_, OUTF_);
}

// Round 6
// 461.754 us; speedup vs baseline: 1.9683x; 1.0191x over previous
//
#include <hip/hip_runtime.h>
#include <hip/hip_bf16.h>

// Problem constants (from reference)
#define NNODES 10000
#define NEDGES 320000
#define INF_   1280
#define HID_   128
#define HEADS_ 4
#define OUTF_  500
#define HC_    512          // HEADS_*HID_
#define NEG_SLOPE 0.2f
#define BN_EPS 1e-5f

typedef __attribute__((ext_vector_type(8))) short short8x;
typedef __attribute__((ext_vector_type(4))) float f32x4;
typedef unsigned short ushort_t;
typedef unsigned int uint_t;

__device__ __forceinline__ ushort_t f2bf(float f) {
    uint_t u = __float_as_uint(f);
    u = (u + 0x7fffu + ((u >> 16) & 1u)) >> 16;   // round-to-nearest-even
    return (ushort_t)u;
}
__device__ __forceinline__ float bf_lo(uint_t p) { return __uint_as_float(p << 16); }
__device__ __forceinline__ float bf_hi(uint_t p) { return __uint_as_float(p & 0xffff0000u); }
__device__ __forceinline__ float lrelu(float x) { return (x >= 0.f) ? x : NEG_SLOPE * x; }
__device__ __forceinline__ uint_t pack_bf16_rn(float a, float b) {
    __hip_bfloat162 h = __float22bfloat162_rn(make_float2(a, b));  // hw packed cvt, RNE
    return *(uint_t*)&h;
}

// ---------------------------------------------------------------------------
// convall: x->bf16 + 3 weight transposes + zero counts.
// R3 lesson: no cross-XCD-shared atomic accumulators (bypass L2 -> HBM txns).
// R5 lesson: fusion pays only if fused work < removed dispatch gap (~8µs).
// ---------------------------------------------------------------------------
#define CVX (NNODES * INF_ / 4)        // 3,200,000 float4 chunks of x
#define CN1 (HC_ * INF_)
#define CN2 (HC_ * HC_)
#define CN3 (HC_ * HC_)                // Wt3 (padded rows)
#define CZC (NNODES / 4)               // counts as uint4 (10000 ints = 2500)
__global__ void convall_kernel(const float* __restrict__ x,
                               const float* __restrict__ W1,
                               const float* __restrict__ W2,
                               const float* __restrict__ W3,
                               ushort_t* __restrict__ x_bf,
                               ushort_t* __restrict__ Wt1,
                               ushort_t* __restrict__ Wt2,
                               ushort_t* __restrict__ Wt3,
                               uint4* __restrict__ zc) {   // counts
    int i = blockIdx.x * blockDim.x + threadIdx.x;
    if (i < CVX) {
        float4 v = ((const float4*)x)[i];
        ((uint2*)x_bf)[i] = make_uint2(pack_bf16_rn(v.x, v.y), pack_bf16_rn(v.z, v.w));
    } else if (i < CVX + CN1) {
        int j = i - CVX;
        int n = j / INF_, k = j - n * INF_;
        Wt1[j] = f2bf(W1[(size_t)k * HC_ + n]);
    } else if (i < CVX + CN1 + CN2) {
        int j = i - CVX - CN1;
        int n = j / HC_, k = j - n * HC_;
        Wt2[j] = f2bf(W2[(size_t)k * HC_ + n]);
    } else if (i < CVX + CN1 + CN2 + CN3) {
        int j = i - CVX - CN1 - CN2;
        int n = j / HC_, k = j - n * HC_;
        Wt3[j] = (n < OUTF_) ? f2bf(W3[(size_t)k * OUTF_ + n]) : (ushort_t)0;
    } else if (i < CVX + CN1 + CN2 + CN3 + CZC) {
        zc[i - CVX - CN1 - CN2 - CN3] = make_uint4(0, 0, 0, 0);
    }
}

// ---------------------------------------------------------------------------
// CSR build (by destination)
// ---------------------------------------------------------------------------
__global__ void count_kernel(const int* __restrict__ dst, int* __restrict__ counts, int E) {
    int e = blockIdx.x * blockDim.x + threadIdx.x;
    if (e < E) atomicAdd(&counts[dst[e]], 1);
}

// single-workgroup scan, wave-shuffle version: 2 barriers (R5: 20-barrier
// Hillis-Steele on one CU ate the fusion gain).
__global__ __launch_bounds__(1024) void scan_fused_kernel(const int* __restrict__ counts,
                                                          int* __restrict__ offsets,
                                                          int* __restrict__ cursor, int n) {
    __shared__ int wsum[16];
    int t = threadIdx.x;
    int lane = t & 63, wv = t >> 6;
    int base = t * 10;
    int v[10];
    int s = 0;
#pragma unroll
    for (int k = 0; k < 10; ++k) {
        int i = base + k;
        int c = (i < n) ? counts[i] : 0;
        v[k] = s;              // exclusive within-thread prefix
        s += c;
    }
    // inclusive wave scan of per-thread sums
    int incl = s;
#pragma unroll
    for (int off = 1; off < 64; off <<= 1) {
        int u = __shfl_up(incl, off, 64);
        if (lane >= off) incl += u;
    }
    if (lane == 63) wsum[wv] = incl;
    __syncthreads();
    if (t < 16) {
        int ws = wsum[t];
        int in2 = ws;
#pragma unroll
        for (int off = 1; off < 16; off <<= 1) {
            int u = __shfl_up(in2, off, 64);
            if (t >= off) in2 += u;
        }
        wsum[t] = in2 - ws;    // exclusive wave prefix
    }
    __syncthreads();
    int basep = wsum[wv] + (incl - s);
#pragma unroll
    for (int k = 0; k < 10; ++k) {
        int i = base + k;
        if (i < n) {
            int o = basep + v[k];
            offsets[i] = o;
            cursor[i] = o;
        }
    }
    if (t == 1023) offsets[n] = basep + s;
}

__global__ void scatter_kernel(const int* __restrict__ src, const int* __restrict__ dst,
                               int* __restrict__ cursor, int* __restrict__ esrc, int E) {
    int e = blockIdx.x * blockDim.x + threadIdx.x;
    if (e < E) {
        int p = atomicAdd(&cursor[dst[e]], 1);
        esrc[p] = src[e];
    }
}

// ---------------------------------------------------------------------------
// bf16 MFMA GEMM — 64(M) x 128(N) tile, BK=32, register-prefetch pipeline
// (proven structure) + FUSED LOGITS EPILOGUE:
//   LOGIT==4 (L1/L2): block col-tile == one head; s,d computed from f32 acc
//     (4 FMA/row/lane + 16-lane shfl reduce + 1KB LDS cross-wave combine),
//     stored directly to s_log[row*4+head].
//   LOGIT==1 (L3): cols masked at OUTF_, per-block partials atomicAdd into
//     s_log/d_log (80K atomics total — fine; R3's disaster was 10.2M).
// Removes the 3 logits dispatches + 30.7MB of xpb re-reads.
// ---------------------------------------------------------------------------
#define LDT 40

template<int LOGIT>
__global__ __launch_bounds__(256) void gemm_kernel(
    const ushort_t* __restrict__ A,    // [M][K] bf16
    const ushort_t* __restrict__ Bt,   // [512][K] bf16 (transposed, padded)
    ushort_t* __restrict__ Cb,         // [M][512] bf16
    const float* __restrict__ aS,      // flat [HC] (L1/L2) or [OUTF] (L3)
    const float* __restrict__ aD,
    float* __restrict__ s_log,         // [N][LOGIT]
    float* __restrict__ d_log,
    int M, int K)
{
    __shared__ __align__(16) ushort_t As[64 * LDT];
    __shared__ __align__(16) ushort_t Bs[128 * LDT];
    __shared__ float sred[64][2], dred[64][2];

    int m0 = blockIdx.y * 64;
    int n0 = blockIdx.x * 128;

    int tid  = threadIdx.x;
    int lane = tid & 63;
    int w    = tid >> 6;
    int wm   = (w & 1) * 32;       // wave m-offset
    int wn   = (w >> 1) * 64;      // wave n-offset
    int quad = lane >> 4;
    int c16  = lane & 15;

    f32x4 acc[2][4];
#pragma unroll
    for (int i = 0; i < 2; ++i)
#pragma unroll
        for (int j = 0; j < 4; ++j)
#pragma unroll
            for (int r = 0; r < 4; ++r) acc[i][j][r] = 0.0f;

    // staging coords
    int sr = tid >> 2;              // A row 0..63
    int sk = (tid & 3) * 8;         // A k-chunk
    int gm = m0 + sr;  if (gm > M - 1) gm = M - 1;
    const ushort_t* aptr = A + (size_t)gm * K + sk;
    int br0 = tid >> 2;             // B rows (2 chunks/thread)
    int bk0 = (tid & 3) * 8;
    int br1 = (256 + tid) >> 2;
    int bk1 = bk0;
    const ushort_t* bptr0 = Bt + (size_t)(n0 + br0) * K + bk0;
    const ushort_t* bptr1 = Bt + (size_t)(n0 + br1) * K + bk1;

    uint4 av  = *(const uint4*)(aptr);
    uint4 bv0 = *(const uint4*)(bptr0);
    uint4 bv1 = *(const uint4*)(bptr1);

    for (int k0 = 0; k0 < K; k0 += 32) {
        *(uint4*)&As[sr * LDT + sk]   = av;
        *(uint4*)&Bs[br0 * LDT + bk0] = bv0;
        *(uint4*)&Bs[br1 * LDT + bk1] = bv1;
        __syncthreads();

        short8x af0 = *(const short8x*)&As[(wm +      c16) * LDT + quad * 8];
        short8x af1 = *(const short8x*)&As[(wm + 16 + c16) * LDT + quad * 8];
        short8x bf[4];
#pragma unroll
        for (int nt = 0; nt < 4; ++nt)
            bf[nt] = *(const short8x*)&Bs[(wn + nt * 16 + c16) * LDT + quad * 8];

        // prefetch next iteration's tiles (in flight across MFMAs + barrier)
        if (k0 + 32 < K) {
            av  = *(const uint4*)(aptr  + k0 + 32);
            bv0 = *(const uint4*)(bptr0 + k0 + 32);
            bv1 = *(const uint4*)(bptr1 + k0 + 32);
        }

#pragma unroll
        for (int nt = 0; nt < 4; ++nt) {
            acc[0][nt] = __builtin_amdgcn_mfma_f32_16x16x32_bf16(af0, bf[nt], acc[0][nt], 0, 0, 0);
            acc[1][nt] = __builtin_amdgcn_mfma_f32_16x16x32_bf16(af1, bf[nt], acc[1][nt], 0, 0, 0);
        }
        __syncthreads();
    }

    // ---- C store ----
#pragma unroll
    for (int mt = 0; mt < 2; ++mt) {
#pragma unroll
        for (int r = 0; r < 4; ++r) {
            int row = m0 + wm + mt * 16 + quad * 4 + r;
            if (row < M) {
#pragma unroll
                for (int nt = 0; nt < 4; ++nt) {
                    int col = n0 + wn + nt * 16 + c16;
                    Cb[(size_t)row * 512 + col] = f2bf(acc[mt][nt][r]);
                }
            }
        }
    }

    // ---- fused logits epilogue ----
    float as_[4], ad_[4];
#pragma unroll
    for (int nt = 0; nt < 4; ++nt) {
        int colg = n0 + wn + nt * 16 + c16;     // global output column
        if (LOGIT == 4) {
            as_[nt] = aS[colg];                  // a_src flat over HC == col index
            ad_[nt] = aD[colg];
        } else {
            as_[nt] = (colg < OUTF_) ? aS[colg] : 0.f;
            ad_[nt] = (colg < OUTF_) ? aD[colg] : 0.f;
        }
    }
#pragma unroll
    for (int mt = 0; mt < 2; ++mt) {
#pragma unroll
        for (int r = 0; r < 4; ++r) {
            float ps = acc[mt][0][r] * as_[0] + acc[mt][1][r] * as_[1]
                     + acc[mt][2][r] * as_[2] + acc[mt][3][r] * as_[3];
            float pd = acc[mt][0][r] * ad_[0] + acc[mt][1][r] * ad_[1]
                     + acc[mt][2][r] * ad_[2] + acc[mt][3][r] * ad_[3];
#pragma unroll
            for (int off = 1; off < 16; off <<= 1) {
                ps += __shfl_xor(ps, off);
                pd += __shfl_xor(pd, off);
            }
            if (c16 == 0) {
                int rl = wm + mt * 16 + quad * 4 + r;   // 0..63
                sred[rl][wn >> 6] = ps;
                dred[rl][wn >> 6] = pd;
            }
        }
    }
    __syncthreads();
    if (tid < 64) {
        int row = m0 + tid;
        if (row < M) {
            float s = sred[tid][0] + sred[tid][1];
            float d = dred[tid][0] + dred[tid][1];
            if (LOGIT == 4) {
                int h = n0 >> 7;                 // block col-tile == head
                s_log[row * 4 + h] = s;
                d_log[row * 4 + h] = d;
            } else {
                atomicAdd(&s_log[row], s);
                atomicAdd(&d_log[row], d);
            }
        }
    }
}

// ---------------------------------------------------------------------------
// FUSED softmax+gather (no BN epilogue — R3 lesson).
//   out = (x_self + Σ_j w_j x_{src_j}) / (1 + Σ_j w_j),
//   w_j = exp(lrelu(s[src_j]+d[n]) - c0),  c0 = self logit (shift; w_self=1).
// Slicing (proven): slice pinned per XCD pair, 2.56 MB L2-resident.
// ---------------------------------------------------------------------------
__device__ __forceinline__ void acc8(float* acc, uint4 q, float w) {
    acc[0] += w * bf_lo(q.x); acc[1] += w * bf_hi(q.x);
    acc[2] += w * bf_lo(q.y); acc[3] += w * bf_hi(q.y);
    acc[4] += w * bf_lo(q.z); acc[5] += w * bf_hi(q.z);
    acc[6] += w * bf_lo(q.w); acc[7] += w * bf_hi(q.w);
}

template<int H>
__global__ __launch_bounds__(256) void gather_fused_kernel(
    const uint4* __restrict__ xpb4,     // [node][64]
    const int* __restrict__ offsets, const int* __restrict__ esrc,
    const float* __restrict__ s_log,    // [node][H]
    const float* __restrict__ d_log,    // [node][H]
    const float* __restrict__ bias,     // [OUTC]
    float* __restrict__ out,            // [node][ldo]
    int OUTC, int ldo)
{
    int id = blockIdx.x;
    int xcd = id & 7;
    int slice = xcd >> 1;                       // 0..3 — pinned per XCD pair
    int sub2 = xcd & 1;
    int wv = threadIdx.x >> 6;
    int node = (id >> 3) * 8 + sub2 * 4 + wv;
    if (node >= NNODES) return;
    int lane = threadIdx.x & 63;
    int esub = lane >> 4;                       // edge subgroup 0..3
    int l16 = lane & 15;
    int h = (H == 4) ? slice : 0;
    int rowoff = slice * 16 + l16;              // uint4 index within 64-wide row

    // node-constant attention terms
    float dh = d_log[node * H + h];
    float c0 = lrelu(s_log[node * H + h] + dh); // self-loop logit = shift

    float acc[8];
    float z;
    if (esub == 0) {
        // self loop: w = exp(c0 - c0) = 1
        uint4 p = xpb4[(size_t)node * 64 + rowoff];
        acc[0] = bf_lo(p.x); acc[1] = bf_hi(p.x);
        acc[2] = bf_lo(p.y); acc[3] = bf_hi(p.y);
        acc[4] = bf_lo(p.z); acc[5] = bf_hi(p.z);
        acc[6] = bf_lo(p.w); acc[7] = bf_hi(p.w);
        z = 1.0f;
    } else {
#pragma unroll
        for (int k = 0; k < 8; ++k) acc[k] = 0.f;
        z = 0.f;
    }

    int e0 = offsets[node], e1 = offsets[node + 1];
    int j = e0 + esub;
    for (; j + 12 < e1; j += 16) {
        int s0 = esrc[j], s1 = esrc[j + 4], s2 = esrc[j + 8], s3 = esrc[j + 12];
        uint4 q0 = xpb4[(size_t)s0 * 64 + rowoff];
        uint4 q1 = xpb4[(size_t)s1 * 64 + rowoff];
        uint4 q2 = xpb4[(size_t)s2 * 64 + rowoff];
        uint4 q3 = xpb4[(size_t)s3 * 64 + rowoff];
        float w0 = __expf(lrelu(s_log[s0 * H + h] + dh) - c0);
        float w1 = __expf(lrelu(s_log[s1 * H + h] + dh) - c0);
        float w2 = __expf(lrelu(s_log[s2 * H + h] + dh) - c0);
        float w3 = __expf(lrelu(s_log[s3 * H + h] + dh) - c0);
        acc8(acc, q0, w0);
        acc8(acc, q1, w1);
        acc8(acc, q2, w2);
        acc8(acc, q3, w3);
        z += w0 + w1 + w2 + w3;
    }
    for (; j < e1; j += 4) {
        int s0 = esrc[j];
        uint4 q0 = xpb4[(size_t)s0 * 64 + rowoff];
        float w0 = __expf(lrelu(s_log[s0 * H + h] + dh) - c0);
        acc8(acc, q0, w0);
        z += w0;
    }

    // combine the 4 edge subgroups
#pragma unroll
    for (int k = 0; k < 8; ++k) {
        acc[k] += __shfl_xor(acc[k], 16);
        acc[k] += __shfl_xor(acc[k], 32);
    }
    z += __shfl_xor(z, 16);
    z += __shfl_xor(z, 32);

    if (esub == 0) {
        float zi = 1.0f / z;
        int cbase = slice * 128 + l16 * 8;
        size_t ob = (size_t)node * ldo + cbase;
        if (cbase + 7 < OUTC) {
            float4 o0 = make_float4(acc[0] * zi + bias[cbase + 0], acc[1] * zi + bias[cbase + 1],
                                    acc[2] * zi + bias[cbase + 2], acc[3] * zi + bias[cbase + 3]);
            float4 o1 = make_float4(acc[4] * zi + bias[cbase + 4], acc[5] * zi + bias[cbase + 5],
                                    acc[6] * zi + bias[cbase + 6], acc[7] * zi + bias[cbase + 7]);
            *(float4*)(out + ob) = o0;
            *(float4*)(out + ob + 4) = o1;
        } else {
#pragma unroll
            for (int k = 0; k < 8; ++k) {
                int c = cbase + k;
                if (c < OUTC) out[ob + k] = acc[k] * zi + bias[c];
            }
        }
    }
}

// ---------------------------------------------------------------------------
// BatchNorm: stats (64-block partials, plain writes) -> apply w/ inline
// finalize. bn_apply optionally zeroes the L3 logit accumulators (zs/zd).
// ---------------------------------------------------------------------------
__global__ __launch_bounds__(512) void bn_stats_kernel(const float* __restrict__ h,
                                                       float* __restrict__ psum,
                                                       float* __restrict__ psumsq) {
    int c = threadIdx.x;  // 512
    int b = blockIdx.x;   // 64
    float sm = 0.f, sq = 0.f;
    for (int r = b; r < NNODES; r += 64) {
        float v = h[(size_t)r * 512 + c];
        sm += v;
        sq += v * v;
    }
    psum[b * 512 + c] = sm;
    psumsq[b * 512 + c] = sq;
}

__global__ __launch_bounds__(256) void bn_apply_kernel(const float* __restrict__ h,
                                                       const float* __restrict__ psum,
                                                       const float* __restrict__ psumsq,
                                                       const float* __restrict__ gamma,
                                                       const float* __restrict__ beta,
                                                       uint_t* __restrict__ hbf,
                                                       float* __restrict__ zs,
                                                       float* __restrict__ zd) {
    int t = threadIdx.x, b = blockIdx.x;   // grid = 256
    if (zs) {
        int gid = b * 256 + t;
        if (gid < NNODES) { zs[gid] = 0.f; zd[gid] = 0.f; }
    }
    int c0 = t * 2, c1 = c0 + 1;
    // inline finalize: reduce 64 banks for this thread's two channels
    float sm0 = 0.f, sq0 = 0.f, sm1 = 0.f, sq1 = 0.f;
    for (int k = 0; k < 64; ++k) {
        sm0 += psum[k * 512 + c0];   sq0 += psumsq[k * 512 + c0];
        sm1 += psum[k * 512 + c1];   sq1 += psumsq[k * 512 + c1];
    }
    const float invN = 1.0f / (float)NNODES;
    float mu0 = sm0 * invN, mu1 = sm1 * invN;
    float var0 = sq0 * invN - mu0 * mu0;
    float var1 = sq1 * invN - mu1 * mu1;
    float sc0 = gamma[c0] * rsqrtf(var0 + BN_EPS);
    float sc1 = gamma[c1] * rsqrtf(var1 + BN_EPS);
    float sh0 = beta[c0] - mu0 * sc0;
    float sh1 = beta[c1] - mu1 * sc1;
    for (int r = b; r < NNODES; r += 256) {
        float2 hv = ((const float2*)(h + (size_t)r * 512))[t];
        float v0 = hv.x * sc0 + sh0;
        float v1 = hv.y * sc1 + sh1;
        v0 = (v0 > 0.f) ? v0 : (__expf(v0) - 1.0f);
        v1 = (v1 > 0.f) ? v1 : (__expf(v1) - 1.0f);
        hbf[r * 256 + t] = ((uint_t)f2bf(v1) << 16) | (uint_t)f2bf(v0);
    }
}

// ---------------------------------------------------------------------------
// launch — 14 dispatches
// ---------------------------------------------------------------------------
extern "C" void kernel_launch(void* const* d_in, const int* in_sizes, int n_in,
                              void* d_out, int out_size, void* d_ws, size_t ws_size,
                              hipStream_t stream) {
    const float* x      = (const float*)d_in[0];
    const int*   ei     = (const int*)d_in[1];
    const float* W1     = (const float*)d_in[2];
    const float* a_src1 = (const float*)d_in[3];
    const float* a_dst1 = (const float*)d_in[4];
    const float* b1     = (const float*)d_in[5];
    const float* g1     = (const float*)d_in[6];
    const float* be1    = (const float*)d_in[7];
    const float* W2     = (const float*)d_in[8];
    const float* a_src2 = (const float*)d_in[9];
    const float* a_dst2 = (const float*)d_in[10];
    const float* b2     = (const float*)d_in[11];
    const float* g2     = (const float*)d_in[12];
    const float* be2    = (const float*)d_in[13];
    const float* W3     = (const float*)d_in[14];
    const float* a_src3 = (const float*)d_in[15];
    const float* a_dst3 = (const float*)d_in[16];
    const float* b3     = (const float*)d_in[17];
    float* out = (float*)d_out;

    const int* e_src = ei;           // edge_index[0]
    const int* e_dst = ei + NEDGES;  // edge_index[1]

    // ---- workspace layout ----
    char* w = (char*)d_ws;
    ushort_t* x_bf = (ushort_t*)w;
    float*    hbuf = (float*)w;                               // alias after L1 GEMM
    w += (size_t)NNODES * INF_ * sizeof(ushort_t);            // 25.6 MB
    uint_t* xpb = (uint_t*)w;  w += (size_t)NNODES * HC_ * sizeof(ushort_t);
    uint_t* hbf = (uint_t*)w;  w += (size_t)NNODES * HC_ * sizeof(ushort_t);
    ushort_t* Wt1 = (ushort_t*)w; w += (size_t)HC_ * INF_ * sizeof(ushort_t);
    ushort_t* Wt2 = (ushort_t*)w; w += (size_t)HC_ * HC_ * sizeof(ushort_t);
    ushort_t* Wt3 = (ushort_t*)w; w += (size_t)HC_ * HC_ * sizeof(ushort_t);
    int* counts  = (int*)w;    w += NNODES * sizeof(int);
    float* s_log = (float*)w;  w += NNODES * HEADS_ * sizeof(float);
    float* d_log = (float*)w;  w += NNODES * HEADS_ * sizeof(float);
    float* psum  = (float*)w;  w += 64 * HC_ * sizeof(float);
    float* psumsq= (float*)w;  w += 64 * HC_ * sizeof(float);
    int* offsets = (int*)w;    w += (NNODES + 1) * sizeof(int);
    int* cursor  = (int*)w;    w += NNODES * sizeof(int);
    int* esrc    = (int*)w;    w += NEDGES * sizeof(int);

    dim3 gg(HC_ / 128, (NNODES + 63) / 64);          // (4, 157) — 64x128 tile
    const int gaGrid = ((NNODES + 7) / 8) * 8;       // 10000 (sliced gather)

    {
        int TOT = CVX + CN1 + CN2 + CN3 + CZC;
        convall_kernel<<<(TOT + 255) / 256, 256, 0, stream>>>(x, W1, W2, W3,
            x_bf, Wt1, Wt2, Wt3, (uint4*)counts);
    }
    count_kernel<<<(NEDGES + 255) / 256, 256, 0, stream>>>(e_dst, counts, NEDGES);
    scan_fused_kernel<<<1, 1024, 0, stream>>>(counts, offsets, cursor, NNODES);
    scatter_kernel<<<(NEDGES + 255) / 256, 256, 0, stream>>>(e_src, e_dst, cursor, esrc, NEDGES);

    // ---- Layer 1 ----
    gemm_kernel<4><<<gg, 256, 0, stream>>>(x_bf, Wt1, (ushort_t*)xpb,
        a_src1, a_dst1, s_log, d_log, NNODES, INF_);
    gather_fused_kernel<HEADS_><<<gaGrid, 256, 0, stream>>>((const uint4*)xpb, offsets, esrc,
        s_log, d_log, b1, hbuf, HC_, HC_);
    bn_stats_kernel<<<64, 512, 0, stream>>>(hbuf, psum, psumsq);
    bn_apply_kernel<<<256, 256, 0, stream>>>(hbuf, psum, psumsq, g1, be1, hbf, nullptr, nullptr);

    // ---- Layer 2 ----
    gemm_kernel<4><<<gg, 256, 0, stream>>>((const ushort_t*)hbf, Wt2, (ushort_t*)xpb,
        a_src2, a_dst2, s_log, d_log, NNODES, HC_);
    gather_fused_kernel<HEADS_><<<gaGrid, 256, 0, stream>>>((const uint4*)xpb, offsets, esrc,
        s_log, d_log, b2, hbuf, HC_, HC_);
    bn_stats_kernel<<<64, 512, 0, stream>>>(hbuf, psum, psumsq);
    bn_apply_kernel<<<256, 256, 0, stream>>>(hbuf, psum, psumsq, g2, be2, hbf, s_log, d_log);

    // ---- Layer 3 (H=1, N=500; logits accumulated atomically across col-blocks) ----
    gemm_kernel<1><<<gg, 256, 0, stream>>>((const ushort_t*)hbf, Wt3, (ushort_t*)xpb,
        a_src3, a_dst3, s_log, d_log, NNODES, HC_);
    gather_fused_kernel<1><<<gaGrid, 256, 0, stream>>>((const uint4*)xpb, offsets, esrc,
        s_log, d_log, b3, out, OUTF_, OUTF_);
}

// Round 7
// 456.144 us; speedup vs baseline: 1.9925x; 1.0123x over previous
//
#include <hip/hip_runtime.h>
#include <hip/hip_bf16.h>

// Problem constants (from reference)
#define NNODES 10000
#define NEDGES 320000
#define INF_   1280
#define HID_   128
#define HEADS_ 4
#define OUTF_  500
#define HC_    512          // HEADS_*HID_
#define NEG_SLOPE 0.2f
#define BN_EPS 1e-5f

typedef __attribute__((ext_vector_type(8))) short short8x;
typedef __attribute__((ext_vector_type(4))) float f32x4;
typedef unsigned short ushort_t;
typedef unsigned int uint_t;

__device__ __forceinline__ ushort_t f2bf(float f) {
    uint_t u = __float_as_uint(f);
    u = (u + 0x7fffu + ((u >> 16) & 1u)) >> 16;   // round-to-nearest-even
    return (ushort_t)u;
}
__device__ __forceinline__ float bf_lo(uint_t p) { return __uint_as_float(p << 16); }
__device__ __forceinline__ float bf_hi(uint_t p) { return __uint_as_float(p & 0xffff0000u); }
__device__ __forceinline__ float lrelu(float x) { return (x >= 0.f) ? x : NEG_SLOPE * x; }
__device__ __forceinline__ uint_t pack_bf16_rn(float a, float b) {
    __hip_bfloat162 h = __float22bfloat162_rn(make_float2(a, b));  // hw packed cvt, RNE
    return *(uint_t*)&h;
}

// ---------------------------------------------------------------------------
// convall: x->bf16 + 3 weight transposes + zero counts.
// R3 lesson: no cross-XCD-shared atomic accumulators (bypass L2 -> HBM txns).
// R5 lesson: fusion pays only if fused work < removed dispatch gap (~8µs).
// ---------------------------------------------------------------------------
#define CVX (NNODES * INF_ / 4)        // 3,200,000 float4 chunks of x
#define CN1 (HC_ * INF_)
#define CN2 (HC_ * HC_)
#define CN3 (HC_ * HC_)                // Wt3 (padded rows)
#define CZC (NNODES / 4)               // counts as uint4 (10000 ints = 2500)
__global__ void convall_kernel(const float* __restrict__ x,
                               const float* __restrict__ W1,
                               const float* __restrict__ W2,
                               const float* __restrict__ W3,
                               ushort_t* __restrict__ x_bf,
                               ushort_t* __restrict__ Wt1,
                               ushort_t* __restrict__ Wt2,
                               ushort_t* __restrict__ Wt3,
                               uint4* __restrict__ zc) {   // counts
    int i = blockIdx.x * blockDim.x + threadIdx.x;
    if (i < CVX) {
        float4 v = ((const float4*)x)[i];
        ((uint2*)x_bf)[i] = make_uint2(pack_bf16_rn(v.x, v.y), pack_bf16_rn(v.z, v.w));
    } else if (i < CVX + CN1) {
        int j = i - CVX;
        int n = j / INF_, k = j - n * INF_;
        Wt1[j] = f2bf(W1[(size_t)k * HC_ + n]);
    } else if (i < CVX + CN1 + CN2) {
        int j = i - CVX - CN1;
        int n = j / HC_, k = j - n * HC_;
        Wt2[j] = f2bf(W2[(size_t)k * HC_ + n]);
    } else if (i < CVX + CN1 + CN2 + CN3) {
        int j = i - CVX - CN1 - CN2;
        int n = j / HC_, k = j - n * HC_;
        Wt3[j] = (n < OUTF_) ? f2bf(W3[(size_t)k * OUTF_ + n]) : (ushort_t)0;
    } else if (i < CVX + CN1 + CN2 + CN3 + CZC) {
        zc[i - CVX - CN1 - CN2 - CN3] = make_uint4(0, 0, 0, 0);
    }
}

// ---------------------------------------------------------------------------
// CSR build (by destination)
// ---------------------------------------------------------------------------
__global__ void count_kernel(const int* __restrict__ dst, int* __restrict__ counts, int E) {
    int e = blockIdx.x * blockDim.x + threadIdx.x;
    if (e < E) atomicAdd(&counts[dst[e]], 1);
}

// single-workgroup scan, wave-shuffle version: 2 barriers.
__global__ __launch_bounds__(1024) void scan_fused_kernel(const int* __restrict__ counts,
                                                          int* __restrict__ offsets,
                                                          int* __restrict__ cursor, int n) {
    __shared__ int wsum[16];
    int t = threadIdx.x;
    int lane = t & 63, wv = t >> 6;
    int base = t * 10;
    int v[10];
    int s = 0;
#pragma unroll
    for (int k = 0; k < 10; ++k) {
        int i = base + k;
        int c = (i < n) ? counts[i] : 0;
        v[k] = s;              // exclusive within-thread prefix
        s += c;
    }
    // inclusive wave scan of per-thread sums
    int incl = s;
#pragma unroll
    for (int off = 1; off < 64; off <<= 1) {
        int u = __shfl_up(incl, off, 64);
        if (lane >= off) incl += u;
    }
    if (lane == 63) wsum[wv] = incl;
    __syncthreads();
    if (t < 16) {
        int ws = wsum[t];
        int in2 = ws;
#pragma unroll
        for (int off = 1; off < 16; off <<= 1) {
            int u = __shfl_up(in2, off, 64);
            if (t >= off) in2 += u;
        }
        wsum[t] = in2 - ws;    // exclusive wave prefix
    }
    __syncthreads();
    int basep = wsum[wv] + (incl - s);
#pragma unroll
    for (int k = 0; k < 10; ++k) {
        int i = base + k;
        if (i < n) {
            int o = basep + v[k];
            offsets[i] = o;
            cursor[i] = o;
        }
    }
    if (t == 1023) offsets[n] = basep + s;
}

__global__ void scatter_kernel(const int* __restrict__ src, const int* __restrict__ dst,
                               int* __restrict__ cursor, int* __restrict__ esrc, int E) {
    int e = blockIdx.x * blockDim.x + threadIdx.x;
    if (e < E) {
        int p = atomicAdd(&cursor[dst[e]], 1);
        esrc[p] = src[e];
    }
}

// ---------------------------------------------------------------------------
// bf16 MFMA GEMM + fused logits epilogue.
// R6 counters: MfmaUtil 11%, VALUBusy 8%, Occ 17%, FETCH 51MB => LATENCY-bound
// (grid 628 blocks = 2.4/CU) with 2x A over-fetch (col-tiles on different XCDs).
// Fixes this round:
//  * DEPTH-2 register prefetch: k+2's loads issue right after k's LDS reads
//    (~2 iterations = 400+ cyc issue-to-use, covers L2/most HBM latency).
//  * Bijective XCD-chunk swizzle (m204): 4 col-tiles of one A row-panel ->
//    same XCD L2 (~3.2MB A panel + 1.3MB B per XCD, fits 4MB L2).
// ---------------------------------------------------------------------------
#define LDT 40

template<int LOGIT>
__global__ __launch_bounds__(256) void gemm_kernel(
    const ushort_t* __restrict__ A,    // [M][K] bf16
    const ushort_t* __restrict__ Bt,   // [512][K] bf16 (transposed, padded)
    ushort_t* __restrict__ Cb,         // [M][512] bf16
    const float* __restrict__ aS,      // flat [HC] (L1/L2) or [OUTF] (L3)
    const float* __restrict__ aD,
    float* __restrict__ s_log,         // [N][LOGIT]
    float* __restrict__ d_log,
    int M, int K)
{
    __shared__ __align__(16) ushort_t As[64 * LDT];
    __shared__ __align__(16) ushort_t Bs[128 * LDT];
    __shared__ float sred[64][2], dred[64][2];

    // bijective XCD-chunk swizzle (nblk=628: q=78, r=4)
    int nblk = gridDim.x;
    int orig = blockIdx.x;
    int q = nblk >> 3, r = nblk & 7;
    int xcd = orig & 7;
    int lid = (xcd < r ? xcd * (q + 1) : r * (q + 1) + (xcd - r) * q) + (orig >> 3);
    int m0 = (lid >> 2) * 64;     // row panel (consecutive lids share it)
    int n0 = (lid & 3) * 128;

    int tid  = threadIdx.x;
    int lane = tid & 63;
    int w    = tid >> 6;
    int wm   = (w & 1) * 32;       // wave m-offset
    int wn   = (w >> 1) * 64;      // wave n-offset
    int quad = lane >> 4;
    int c16  = lane & 15;

    f32x4 acc[2][4];
#pragma unroll
    for (int i = 0; i < 2; ++i)
#pragma unroll
        for (int j = 0; j < 4; ++j)
#pragma unroll
            for (int r2 = 0; r2 < 4; ++r2) acc[i][j][r2] = 0.0f;

    // staging coords
    int sr = tid >> 2;              // A row 0..63
    int sk = (tid & 3) * 8;         // A k-chunk
    int gm = m0 + sr;  if (gm > M - 1) gm = M - 1;
    const ushort_t* aptr = A + (size_t)gm * K + sk;
    int br0 = tid >> 2;             // B rows (2 chunks/thread)
    int bk0 = (tid & 3) * 8;
    int br1 = (256 + tid) >> 2;
    int bk1 = bk0;
    const ushort_t* bptr0 = Bt + (size_t)(n0 + br0) * K + bk0;
    const ushort_t* bptr1 = Bt + (size_t)(n0 + br1) * K + bk1;

    // depth-2 prefetch registers: *_a = next tile to write, *_b = one behind it
    uint4 av_a  = *(const uint4*)(aptr);
    uint4 bv0_a = *(const uint4*)(bptr0);
    uint4 bv1_a = *(const uint4*)(bptr1);
    uint4 av_b, bv0_b, bv1_b;
    if (K > 32) {
        av_b  = *(const uint4*)(aptr  + 32);
        bv0_b = *(const uint4*)(bptr0 + 32);
        bv1_b = *(const uint4*)(bptr1 + 32);
    }

    for (int k0 = 0; k0 < K; k0 += 32) {
        *(uint4*)&As[sr * LDT + sk]   = av_a;
        *(uint4*)&Bs[br0 * LDT + bk0] = bv0_a;
        *(uint4*)&Bs[br1 * LDT + bk1] = bv1_a;
        __syncthreads();

        short8x af0 = *(const short8x*)&As[(wm +      c16) * LDT + quad * 8];
        short8x af1 = *(const short8x*)&As[(wm + 16 + c16) * LDT + quad * 8];
        short8x bf[4];
#pragma unroll
        for (int nt = 0; nt < 4; ++nt)
            bf[nt] = *(const short8x*)&Bs[(wn + nt * 16 + c16) * LDT + quad * 8];

        // shift pipeline and issue k+2's loads (in flight ~2 iterations)
        av_a = av_b; bv0_a = bv0_b; bv1_a = bv1_b;
        if (k0 + 64 < K) {
            av_b  = *(const uint4*)(aptr  + k0 + 64);
            bv0_b = *(const uint4*)(bptr0 + k0 + 64);
            bv1_b = *(const uint4*)(bptr1 + k0 + 64);
        }

#pragma unroll
        for (int nt = 0; nt < 4; ++nt) {
            acc[0][nt] = __builtin_amdgcn_mfma_f32_16x16x32_bf16(af0, bf[nt], acc[0][nt], 0, 0, 0);
            acc[1][nt] = __builtin_amdgcn_mfma_f32_16x16x32_bf16(af1, bf[nt], acc[1][nt], 0, 0, 0);
        }
        __syncthreads();
    }

    // ---- C store ----
#pragma unroll
    for (int mt = 0; mt < 2; ++mt) {
#pragma unroll
        for (int r2 = 0; r2 < 4; ++r2) {
            int row = m0 + wm + mt * 16 + quad * 4 + r2;
            if (row < M) {
#pragma unroll
                for (int nt = 0; nt < 4; ++nt) {
                    int col = n0 + wn + nt * 16 + c16;
                    Cb[(size_t)row * 512 + col] = f2bf(acc[mt][nt][r2]);
                }
            }
        }
    }

    // ---- fused logits epilogue ----
    float as_[4], ad_[4];
#pragma unroll
    for (int nt = 0; nt < 4; ++nt) {
        int colg = n0 + wn + nt * 16 + c16;     // global output column
        if (LOGIT == 4) {
            as_[nt] = aS[colg];                  // a_src flat over HC == col index
            ad_[nt] = aD[colg];
        } else {
            as_[nt] = (colg < OUTF_) ? aS[colg] : 0.f;
            ad_[nt] = (colg < OUTF_) ? aD[colg] : 0.f;
        }
    }
#pragma unroll
    for (int mt = 0; mt < 2; ++mt) {
#pragma unroll
        for (int r2 = 0; r2 < 4; ++r2) {
            float ps = acc[mt][0][r2] * as_[0] + acc[mt][1][r2] * as_[1]
                     + acc[mt][2][r2] * as_[2] + acc[mt][3][r2] * as_[3];
            float pd = acc[mt][0][r2] * ad_[0] + acc[mt][1][r2] * ad_[1]
                     + acc[mt][2][r2] * ad_[2] + acc[mt][3][r2] * ad_[3];
#pragma unroll
            for (int off = 1; off < 16; off <<= 1) {
                ps += __shfl_xor(ps, off);
                pd += __shfl_xor(pd, off);
            }
            if (c16 == 0) {
                int rl = wm + mt * 16 + quad * 4 + r2;   // 0..63
                sred[rl][wn >> 6] = ps;
                dred[rl][wn >> 6] = pd;
            }
        }
    }
    __syncthreads();
    if (tid < 64) {
        int row = m0 + tid;
        if (row < M) {
            float s = sred[tid][0] + sred[tid][1];
            float d = dred[tid][0] + dred[tid][1];
            if (LOGIT == 4) {
                int h = n0 >> 7;                 // block col-tile == head
                s_log[row * 4 + h] = s;
                d_log[row * 4 + h] = d;
            } else {
                atomicAdd(&s_log[row], s);
                atomicAdd(&d_log[row], d);
            }
        }
    }
}

// ---------------------------------------------------------------------------
// FUSED softmax+gather (no BN epilogue — R3 lesson).
//   out = (x_self + Σ_j w_j x_{src_j}) / (1 + Σ_j w_j),
//   w_j = exp(lrelu(s[src_j]+d[n]) - c0),  c0 = self logit (shift; w_self=1).
// Slicing (proven): slice pinned per XCD pair, 2.56 MB L2-resident.
// ---------------------------------------------------------------------------
__device__ __forceinline__ void acc8(float* acc, uint4 q, float w) {
    acc[0] += w * bf_lo(q.x); acc[1] += w * bf_hi(q.x);
    acc[2] += w * bf_lo(q.y); acc[3] += w * bf_hi(q.y);
    acc[4] += w * bf_lo(q.z); acc[5] += w * bf_hi(q.z);
    acc[6] += w * bf_lo(q.w); acc[7] += w * bf_hi(q.w);
}

template<int H>
__global__ __launch_bounds__(256) void gather_fused_kernel(
    const uint4* __restrict__ xpb4,     // [node][64]
    const int* __restrict__ offsets, const int* __restrict__ esrc,
    const float* __restrict__ s_log,    // [node][H]
    const float* __restrict__ d_log,    // [node][H]
    const float* __restrict__ bias,     // [OUTC]
    float* __restrict__ out,            // [node][ldo]
    int OUTC, int ldo)
{
    int id = blockIdx.x;
    int xcd = id & 7;
    int slice = xcd >> 1;                       // 0..3 — pinned per XCD pair
    int sub2 = xcd & 1;
    int wv = threadIdx.x >> 6;
    int node = (id >> 3) * 8 + sub2 * 4 + wv;
    if (node >= NNODES) return;
    int lane = threadIdx.x & 63;
    int esub = lane >> 4;                       // edge subgroup 0..3
    int l16 = lane & 15;
    int h = (H == 4) ? slice : 0;
    int rowoff = slice * 16 + l16;              // uint4 index within 64-wide row

    // node-constant attention terms
    float dh = d_log[node * H + h];
    float c0 = lrelu(s_log[node * H + h] + dh); // self-loop logit = shift

    float acc[8];
    float z;
    if (esub == 0) {
        // self loop: w = exp(c0 - c0) = 1
        uint4 p = xpb4[(size_t)node * 64 + rowoff];
        acc[0] = bf_lo(p.x); acc[1] = bf_hi(p.x);
        acc[2] = bf_lo(p.y); acc[3] = bf_hi(p.y);
        acc[4] = bf_lo(p.z); acc[5] = bf_hi(p.z);
        acc[6] = bf_lo(p.w); acc[7] = bf_hi(p.w);
        z = 1.0f;
    } else {
#pragma unroll
        for (int k = 0; k < 8; ++k) acc[k] = 0.f;
        z = 0.f;
    }

    int e0 = offsets[node], e1 = offsets[node + 1];
    int j = e0 + esub;
    for (; j + 12 < e1; j += 16) {
        int s0 = esrc[j], s1 = esrc[j + 4], s2 = esrc[j + 8], s3 = esrc[j + 12];
        uint4 q0 = xpb4[(size_t)s0 * 64 + rowoff];
        uint4 q1 = xpb4[(size_t)s1 * 64 + rowoff];
        uint4 q2 = xpb4[(size_t)s2 * 64 + rowoff];
        uint4 q3 = xpb4[(size_t)s3 * 64 + rowoff];
        float w0 = __expf(lrelu(s_log[s0 * H + h] + dh) - c0);
        float w1 = __expf(lrelu(s_log[s1 * H + h] + dh) - c0);
        float w2 = __expf(lrelu(s_log[s2 * H + h] + dh) - c0);
        float w3 = __expf(lrelu(s_log[s3 * H + h] + dh) - c0);
        acc8(acc, q0, w0);
        acc8(acc, q1, w1);
        acc8(acc, q2, w2);
        acc8(acc, q3, w3);
        z += w0 + w1 + w2 + w3;
    }
    for (; j < e1; j += 4) {
        int s0 = esrc[j];
        uint4 q0 = xpb4[(size_t)s0 * 64 + rowoff];
        float w0 = __expf(lrelu(s_log[s0 * H + h] + dh) - c0);
        acc8(acc, q0, w0);
        z += w0;
    }

    // combine the 4 edge subgroups
#pragma unroll
    for (int k = 0; k < 8; ++k) {
        acc[k] += __shfl_xor(acc[k], 16);
        acc[k] += __shfl_xor(acc[k], 32);
    }
    z += __shfl_xor(z, 16);
    z += __shfl_xor(z, 32);

    if (esub == 0) {
        float zi = 1.0f / z;
        int cbase = slice * 128 + l16 * 8;
        size_t ob = (size_t)node * ldo + cbase;
        if (cbase + 7 < OUTC) {
            float4 o0 = make_float4(acc[0] * zi + bias[cbase + 0], acc[1] * zi + bias[cbase + 1],
                                    acc[2] * zi + bias[cbase + 2], acc[3] * zi + bias[cbase + 3]);
            float4 o1 = make_float4(acc[4] * zi + bias[cbase + 4], acc[5] * zi + bias[cbase + 5],
                                    acc[6] * zi + bias[cbase + 6], acc[7] * zi + bias[cbase + 7]);
            *(float4*)(out + ob) = o0;
            *(float4*)(out + ob + 4) = o1;
        } else {
#pragma unroll
            for (int k = 0; k < 8; ++k) {
                int c = cbase + k;
                if (c < OUTC) out[ob + k] = acc[k] * zi + bias[c];
            }
        }
    }
}

// ---------------------------------------------------------------------------
// BatchNorm: stats (64-block partials, plain writes) -> apply w/ inline
// finalize. bn_apply optionally zeroes the L3 logit accumulators (zs/zd).
// ---------------------------------------------------------------------------
__global__ __launch_bounds__(512) void bn_stats_kernel(const float* __restrict__ h,
                                                       float* __restrict__ psum,
                                                       float* __restrict__ psumsq) {
    int c = threadIdx.x;  // 512
    int b = blockIdx.x;   // 64
    float sm = 0.f, sq = 0.f;
    for (int r = b; r < NNODES; r += 64) {
        float v = h[(size_t)r * 512 + c];
        sm += v;
        sq += v * v;
    }
    psum[b * 512 + c] = sm;
    psumsq[b * 512 + c] = sq;
}

__global__ __launch_bounds__(256) void bn_apply_kernel(const float* __restrict__ h,
                                                       const float* __restrict__ psum,
                                                       const float* __restrict__ psumsq,
                                                       const float* __restrict__ gamma,
                                                       const float* __restrict__ beta,
                                                       uint_t* __restrict__ hbf,
                                                       float* __restrict__ zs,
                                                       float* __restrict__ zd) {
    int t = threadIdx.x, b = blockIdx.x;   // grid = 256
    if (zs) {
        int gid = b * 256 + t;
        if (gid < NNODES) { zs[gid] = 0.f; zd[gid] = 0.f; }
    }
    int c0 = t * 2, c1 = c0 + 1;
    // inline finalize: reduce 64 banks for this thread's two channels
    float sm0 = 0.f, sq0 = 0.f, sm1 = 0.f, sq1 = 0.f;
    for (int k = 0; k < 64; ++k) {
        sm0 += psum[k * 512 + c0];   sq0 += psumsq[k * 512 + c0];
        sm1 += psum[k * 512 + c1];   sq1 += psumsq[k * 512 + c1];
    }
    const float invN = 1.0f / (float)NNODES;
    float mu0 = sm0 * invN, mu1 = sm1 * invN;
    float var0 = sq0 * invN - mu0 * mu0;
    float var1 = sq1 * invN - mu1 * mu1;
    float sc0 = gamma[c0] * rsqrtf(var0 + BN_EPS);
    float sc1 = gamma[c1] * rsqrtf(var1 + BN_EPS);
    float sh0 = beta[c0] - mu0 * sc0;
    float sh1 = beta[c1] - mu1 * sc1;
    for (int r = b; r < NNODES; r += 256) {
        float2 hv = ((const float2*)(h + (size_t)r * 512))[t];
        float v0 = hv.x * sc0 + sh0;
        float v1 = hv.y * sc1 + sh1;
        v0 = (v0 > 0.f) ? v0 : (__expf(v0) - 1.0f);
        v1 = (v1 > 0.f) ? v1 : (__expf(v1) - 1.0f);
        hbf[r * 256 + t] = ((uint_t)f2bf(v1) << 16) | (uint_t)f2bf(v0);
    }
}

// ---------------------------------------------------------------------------
// launch — 14 dispatches
// ---------------------------------------------------------------------------
extern "C" void kernel_launch(void* const* d_in, const int* in_sizes, int n_in,
                              void* d_out, int out_size, void* d_ws, size_t ws_size,
                              hipStream_t stream) {
    const float* x      = (const float*)d_in[0];
    const int*   ei     = (const int*)d_in[1];
    const float* W1     = (const float*)d_in[2];
    const float* a_src1 = (const float*)d_in[3];
    const float* a_dst1 = (const float*)d_in[4];
    const float* b1     = (const float*)d_in[5];
    const float* g1     = (const float*)d_in[6];
    const float* be1    = (const float*)d_in[7];
    const float* W2     = (const float*)d_in[8];
    const float* a_src2 = (const float*)d_in[9];
    const float* a_dst2 = (const float*)d_in[10];
    const float* b2     = (const float*)d_in[11];
    const float* g2     = (const float*)d_in[12];
    const float* be2    = (const float*)d_in[13];
    const float* W3     = (const float*)d_in[14];
    const float* a_src3 = (const float*)d_in[15];
    const float* a_dst3 = (const float*)d_in[16];
    const float* b3     = (const float*)d_in[17];
    float* out = (float*)d_out;

    const int* e_src = ei;           // edge_index[0]
    const int* e_dst = ei + NEDGES;  // edge_index[1]

    // ---- workspace layout ----
    char* w = (char*)d_ws;
    ushort_t* x_bf = (ushort_t*)w;
    float*    hbuf = (float*)w;                               // alias after L1 GEMM
    w += (size_t)NNODES * INF_ * sizeof(ushort_t);            // 25.6 MB
    uint_t* xpb = (uint_t*)w;  w += (size_t)NNODES * HC_ * sizeof(ushort_t);
    uint_t* hbf = (uint_t*)w;  w += (size_t)NNODES * HC_ * sizeof(ushort_t);
    ushort_t* Wt1 = (ushort_t*)w; w += (size_t)HC_ * INF_ * sizeof(ushort_t);
    ushort_t* Wt2 = (ushort_t*)w; w += (size_t)HC_ * HC_ * sizeof(ushort_t);
    ushort_t* Wt3 = (ushort_t*)w; w += (size_t)HC_ * HC_ * sizeof(ushort_t);
    int* counts  = (int*)w;    w += NNODES * sizeof(int);
    float* s_log = (float*)w;  w += NNODES * HEADS_ * sizeof(float);
    float* d_log = (float*)w;  w += NNODES * HEADS_ * sizeof(float);
    float* psum  = (float*)w;  w += 64 * HC_ * sizeof(float);
    float* psumsq= (float*)w;  w += 64 * HC_ * sizeof(float);
    int* offsets = (int*)w;    w += (NNODES + 1) * sizeof(int);
    int* cursor  = (int*)w;    w += NNODES * sizeof(int);
    int* esrc    = (int*)w;    w += NEDGES * sizeof(int);

    const int ggBlocks = (HC_ / 128) * ((NNODES + 63) / 64);   // 628, 1-D + swizzle
    const int gaGrid = ((NNODES + 7) / 8) * 8;       // 10000 (sliced gather)

    {
        int TOT = CVX + CN1 + CN2 + CN3 + CZC;
        convall_kernel<<<(TOT + 255) / 256, 256, 0, stream>>>(x, W1, W2, W3,
            x_bf, Wt1, Wt2, Wt3, (uint4*)counts);
    }
    count_kernel<<<(NEDGES + 255) / 256, 256, 0, stream>>>(e_dst, counts, NEDGES);
    scan_fused_kernel<<<1, 1024, 0, stream>>>(counts, offsets, cursor, NNODES);
    scatter_kernel<<<(NEDGES + 255) / 256, 256, 0, stream>>>(e_src, e_dst, cursor, esrc, NEDGES);

    // ---- Layer 1 ----
    gemm_kernel<4><<<ggBlocks, 256, 0, stream>>>(x_bf, Wt1, (ushort_t*)xpb,
        a_src1, a_dst1, s_log, d_log, NNODES, INF_);
    gather_fused_kernel<HEADS_><<<gaGrid, 256, 0, stream>>>((const uint4*)xpb, offsets, esrc,
        s_log, d_log, b1, hbuf, HC_, HC_);
    bn_stats_kernel<<<64, 512, 0, stream>>>(hbuf, psum, psumsq);
    bn_apply_kernel<<<256, 256, 0, stream>>>(hbuf, psum, psumsq, g1, be1, hbf, nullptr, nullptr);

    // ---- Layer 2 ----
    gemm_kernel<4><<<ggBlocks, 256, 0, stream>>>((const ushort_t*)hbf, Wt2, (ushort_t*)xpb,
        a_src2, a_dst2, s_log, d_log, NNODES, HC_);
    gather_fused_kernel<HEADS_><<<gaGrid, 256, 0, stream>>>((const uint4*)xpb, offsets, esrc,
        s_log, d_log, b2, hbuf, HC_, HC_);
    bn_stats_kernel<<<64, 512, 0, stream>>>(hbuf, psum, psumsq);
    bn_apply_kernel<<<256, 256, 0, stream>>>(hbuf, psum, psumsq, g2, be2, hbf, s_log, d_log);

    // ---- Layer 3 (H=1, N=500; logits accumulated atomically across col-blocks) ----
    gemm_kernel<1><<<ggBlocks, 256, 0, stream>>>((const ushort_t*)hbf, Wt3, (ushort_t*)xpb,
        a_src3, a_dst3, s_log, d_log, NNODES, HC_);
    gather_fused_kernel<1><<<gaGrid, 256, 0, stream>>>((const uint4*)xpb, offsets, esrc,
        s_log, d_log, b3, out, OUTF_, OUTF_);
}